// Round 5
// baseline (310.888 us; speedup 1.0000x reference)
//
#include <hip/hip_runtime.h>
#include <hip/hip_bf16.h>

#define BB 2
#define SS 2048
#define DD 1024
#define HH 16
#define HD 64

typedef __attribute__((ext_vector_type(8))) short bf16x8;
typedef __attribute__((ext_vector_type(4))) float f32x4;

// round-to-nearest-even f32 -> bf16 (inputs finite)
__device__ __forceinline__ unsigned short f2bf(float f) {
  unsigned int u = __float_as_uint(f);
  return (unsigned short)((u + 0x7FFFu + ((u >> 16) & 1u)) >> 16);
}

// 2^x via hardware v_exp_f32
__device__ __forceinline__ float fast_exp2(float x) {
#if __has_builtin(__builtin_amdgcn_exp2f)
  return __builtin_amdgcn_exp2f(x);
#else
  return __expf(x * 0.6931471805599453f);
#endif
}

__device__ __forceinline__ void async_copy16(const unsigned short* gp, unsigned short* lp) {
  __builtin_amdgcn_global_load_lds(
      (const __attribute__((address_space(1))) unsigned int*)gp,
      (__attribute__((address_space(3))) unsigned int*)lp, 16, 0, 0);
}

// gfx950 cross-lane register swaps (VALU, not DS pipe).
__device__ __forceinline__ void pl32_swap(unsigned& a, unsigned& b) {
#if __has_builtin(__builtin_amdgcn_permlane32_swap)
  auto r = __builtin_amdgcn_permlane32_swap(a, b, false, false);
  a = r[0];
  b = r[1];
#else
  asm volatile("v_permlane32_swap_b32 %0, %1" : "+v"(a), "+v"(b));
#endif
}
__device__ __forceinline__ void pl16_swap(unsigned& a, unsigned& b) {
#if __has_builtin(__builtin_amdgcn_permlane16_swap)
  auto r = __builtin_amdgcn_permlane16_swap(a, b, false, false);
  a = r[0];
  b = r[1];
#else
  asm volatile("v_permlane16_swap_b32 %0, %1" : "+v"(a), "+v"(b));
#endif
}

// ---------------------------------------------------------------------------
// Fused prep: blocks [0,4096) convert x -> bf16; blocks [4096,8192) transpose
// one of the 4 weight matrices (1024 32x32 tiles each) to bf16 [N][K].
// ---------------------------------------------------------------------------
__global__ __launch_bounds__(256) void prep_kernel(
    const float* __restrict__ x, unsigned short* __restrict__ xb,
    const float* __restrict__ W0, unsigned short* __restrict__ T0,
    const float* __restrict__ W1, unsigned short* __restrict__ T1,
    const float* __restrict__ W2, unsigned short* __restrict__ T2,
    const float* __restrict__ W3, unsigned short* __restrict__ T3) {
  const int blk = blockIdx.x;
  const int t = threadIdx.x;
  if (blk < 4096) {
    int i = blk * 1024 + t * 4;
    float4 v = *(const float4*)(x + i);
    ushort4 u;
    u.x = f2bf(v.x); u.y = f2bf(v.y); u.z = f2bf(v.z); u.w = f2bf(v.w);
    *(ushort4*)(xb + i) = u;
    return;
  }
  const int j = blk - 4096;
  const int jw = j >> 10;          // which weight
  const int tb = j & 1023;
  const float* W = jw == 0 ? W0 : (jw == 1 ? W1 : (jw == 2 ? W2 : W3));
  unsigned short* T = jw == 0 ? T0 : (jw == 1 ? T1 : (jw == 2 ? T2 : T3));
  __shared__ float tile[32][33];
  int k0 = (tb & 31) * 32, n0 = (tb >> 5) * 32;
  int c = t & 31, r0 = t >> 5;
#pragma unroll
  for (int i = 0; i < 4; ++i) {
    int r = r0 + i * 8;
    tile[r][c] = W[(size_t)(k0 + r) * DD + n0 + c];
  }
  __syncthreads();
#pragma unroll
  for (int i = 0; i < 4; ++i) {
    int r = r0 + i * 8;
    T[(size_t)(n0 + r) * DD + k0 + c] = f2bf(tile[c][r]);
  }
}

// ---------------------------------------------------------------------------
// bf16 MFMA GEMM core (m97 single-buffer, BK=32): D = A[M,K]@B^T[N,K] + bias
// STORE=0: fp32 out [M][DD]   (used by out-projection only)
// ---------------------------------------------------------------------------
template <int STORE>
__device__ __forceinline__ void gemm_core(
    const unsigned short* __restrict__ A, const unsigned short* __restrict__ BT,
    const float* __restrict__ bias, void* __restrict__ outp, float scale,
    int bm, int bn) {
  const int t = threadIdx.x;
  const int w = t >> 6;
  const int l = t & 63;
  const int wm = (w >> 1) * 64;
  const int wn = (w & 1) * 64;

  __shared__ __align__(16) unsigned short As[128 * 32];
  __shared__ __align__(16) unsigned short Bs[128 * 32];

  f32x4 acc[4][4];
#pragma unroll
  for (int i = 0; i < 4; ++i)
#pragma unroll
    for (int j = 0; j < 4; ++j) acc[i][j] = (f32x4)0.f;

  const int fr = l & 15;
  const int kg = (l >> 4) * 8;

  for (int k0 = 0; k0 < DD; k0 += 32) {
    __syncthreads();
#pragma unroll
    for (int c = 0; c < 2; ++c) {
      int e = (w * 2 + c) * 512 + l * 8;
      int row = e >> 5, kk = e & 31;
      async_copy16(A + (size_t)(bm + row) * DD + k0 + kk, As + (w * 2 + c) * 512);
      async_copy16(BT + (size_t)(bn + row) * DD + k0 + kk, Bs + (w * 2 + c) * 512);
    }
    __syncthreads();

    bf16x8 af[4], bfr[4];
#pragma unroll
    for (int i = 0; i < 4; ++i)
      af[i] = *(const bf16x8*)(As + (wm + i * 16 + fr) * 32 + kg);
#pragma unroll
    for (int j = 0; j < 4; ++j)
      bfr[j] = *(const bf16x8*)(Bs + (wn + j * 16 + fr) * 32 + kg);
#pragma unroll
    for (int i = 0; i < 4; ++i)
#pragma unroll
      for (int j = 0; j < 4; ++j)
        acc[i][j] = __builtin_amdgcn_mfma_f32_16x16x32_bf16(af[i], bfr[j], acc[i][j], 0, 0, 0);
  }

  const int col_l = l & 15;
  const int row_l = (l >> 4) * 4;

#pragma unroll
  for (int i = 0; i < 4; ++i) {
    int m_base = bm + wm + i * 16 + row_l;
#pragma unroll
    for (int j = 0; j < 4; ++j) {
      int n = bn + wn + j * 16 + col_l;
      float bv = bias[n];
      float* out = (float*)outp;
#pragma unroll
      for (int r = 0; r < 4; ++r)
        out[(size_t)(m_base + r) * DD + n] = acc[i][j][r] + bv;
    }
  }
}

// output projection, 256 blocks, XCD-swizzled (8 bn per bm on one XCD)
__global__ __launch_bounds__(256) void out_gemm_mfma(
    const unsigned short* __restrict__ A, const unsigned short* __restrict__ WoT,
    const float* __restrict__ bo, float* __restrict__ out) {
  const int i = blockIdx.x;
  const int xcd = i & 7;
  const int slot = i >> 3;            // 0..31
  const int bm = (xcd + 8 * (slot >> 3)) * 128;
  const int bn = (slot & 7) * 128;
  gemm_core<0>(A, WoT, bo, (void*)out, 1.0f, bm, bn);
}

// ---------------------------------------------------------------------------
// QKV projection, 8-phase 256x256xBK64 template (T2+T3+T4+T5). Verified R3:
// dropped out of the top-5 (was 54 us on the 128^2 2-barrier core).
// ---------------------------------------------------------------------------
#define QPHASE(DB, KH, MH, S, VM) do {                                        \
    bf16x8 af[4];                                                             \
    _Pragma("unroll")                                                         \
    for (int ii = 0; ii < 4; ++ii) {                                          \
      int row = wm * 128 + (MH) * 64 + ii * 16 + fr;                          \
      int kb = kg16 ^ ((row & 8) ? 32 : 0) ^ ((row & 4) ? 16 : 0);            \
      af[ii] = *(const bf16x8*)((const char*)&lds[0][DB][KH][0] + row * 64 + kb); \
    }                                                                         \
    if ((MH) == 0) {                                                          \
      _Pragma("unroll")                                                       \
      for (int j = 0; j < 4; ++j) {                                           \
        int row = wn * 64 + j * 16 + fr;                                      \
        int kb = kg16 ^ ((row & 8) ? 32 : 0) ^ ((row & 4) ? 16 : 0);          \
        bfr[j] = *(const bf16x8*)((const char*)&lds[1][DB][KH][0] + row * 64 + kb); \
      }                                                                       \
    }                                                                         \
    stage_half(S);                                                            \
    asm volatile("s_barrier" ::: "memory");                                   \
    __builtin_amdgcn_s_setprio(1);                                            \
    _Pragma("unroll")                                                         \
    for (int ii = 0; ii < 4; ++ii)                                            \
      _Pragma("unroll")                                                       \
      for (int j = 0; j < 4; ++j)                                             \
        acc[(MH) * 4 + ii][j] = __builtin_amdgcn_mfma_f32_16x16x32_bf16(      \
            af[ii], bfr[j], acc[(MH) * 4 + ii][j], 0, 0, 0);                  \
    __builtin_amdgcn_s_setprio(0);                                            \
    if ((VM) == 1) asm volatile("s_waitcnt vmcnt(4)" ::: "memory");           \
    if ((VM) == 2) asm volatile("s_waitcnt vmcnt(0)" ::: "memory");           \
    asm volatile("s_barrier" ::: "memory");                                   \
  } while (0)

__global__ __launch_bounds__(512, 2) void qkv_gemm_8ph(
    const unsigned short* __restrict__ A,
    const unsigned short* __restrict__ WqT, const unsigned short* __restrict__ WkT,
    const unsigned short* __restrict__ WvT,
    const float* __restrict__ bq, const float* __restrict__ bk,
    const float* __restrict__ bv,
    unsigned short* __restrict__ Qo, unsigned short* __restrict__ Ko,
    unsigned short* __restrict__ VTo) {
  const int i = blockIdx.x;
  const int xcd = i & 7;
  const int slot = i >> 3;              // 0..23
  const int bmi = xcd * 2 + (slot / 12);
  const int c = slot % 12;
  const int which = c >> 2;             // 0:Q 1:K 2:V
  const int bm = bmi * 256;
  const int bn = (c & 3) * 256;
  const unsigned short* BT = which == 0 ? WqT : (which == 1 ? WkT : WvT);
  const float* bias = which == 0 ? bq : (which == 1 ? bk : bv);

  const int t = threadIdx.x;
  const int w = t >> 6;
  const int l = t & 63;
  const int wm = w >> 2;        // 0..1 (M)
  const int wn = w & 3;         // 0..3 (N)
  const int fr = l & 15;
  const int kg16 = (l >> 4) * 16;   // byte offset of lane's k-group in 32k half

  // [mat A/B][dbuf][khalf][256 rows x 32 k] bf16, 128 KiB total
  __shared__ __align__(16) unsigned short lds[2][2][2][8192];

  f32x4 acc[8][4];
#pragma unroll
  for (int mi = 0; mi < 8; ++mi)
#pragma unroll
    for (int j = 0; j < 4; ++j) acc[mi][j] = (f32x4)0.f;

  // stage half-tile s (s = 4*T + {0:A_k0,1:B_k0,2:A_k1,3:B_k1}); 2 loads/thr
  auto stage_half = [&](int s) {
    if (s >= 64) return;
    const int Ts = s >> 2;
    const int db = Ts & 1;
    const int typ = s & 3;
    const int kh = typ >> 1;
    const int isB = typ & 1;
    const unsigned short* src = isB ? BT : A;
    const int rbase = isB ? bn : bm;
    unsigned short* dstbase = &lds[isB][db][kh][0];
    const int k0 = Ts * 64 + kh * 32;
#pragma unroll
    for (int j = 0; j < 2; ++j) {
      int cc = (w * 2 + j) * 64 + l;    // 16B chunk 0..1023
      int row = cc >> 2;
      int ke = ((cc & 3) * 8) ^ ((row & 8) ? 16 : 0) ^ ((row & 4) ? 8 : 0);
      async_copy16(src + (size_t)(rbase + row) * DD + k0 + ke,
                   dstbase + (w * 2 + j) * 512);
    }
  };

  bf16x8 bfr[4];

  // prologue: tile0 (4 halves) + tile1 first 2 halves; wait tile0 landed
  for (int s = 0; s < 6; ++s) stage_half(s);
  asm volatile("s_waitcnt vmcnt(4)" ::: "memory");
  asm volatile("s_barrier" ::: "memory");

  for (int T = 0; T < 14; ++T) {
    const int db = T & 1;
    const int sb = 4 * T + 6;
    QPHASE(db, 0, 0, sb + 0, 0);
    QPHASE(db, 0, 1, sb + 1, 0);
    QPHASE(db, 1, 0, sb + 2, 0);
    QPHASE(db, 1, 1, sb + 3, 1);      // boundary: vmcnt(4)
  }
  // T = 14 (db 0): stages s=62,63 then exhausted; final drain at boundary
  QPHASE(0, 0, 0, 62, 0);
  QPHASE(0, 0, 1, 63, 0);
  QPHASE(0, 1, 0, 64, 0);
  QPHASE(0, 1, 1, 64, 2);             // vmcnt(0): everything landed
  // T = 15 (db 1): no staging, no waits needed
  QPHASE(1, 0, 0, 64, 0);
  QPHASE(1, 0, 1, 64, 0);
  QPHASE(1, 1, 0, 64, 0);
  QPHASE(1, 1, 1, 64, 0);

  const int col_l = l & 15;
  const int row_l = (l >> 4) * 4;
  const int b_ = bm >> 11;

  if (which != 2) {
    // Q/K: bf16 out [B,H,S,HD], scaled
    const float scl = which == 0 ? 0.18033688011112042f : 1.0f;
    unsigned short* out = which == 0 ? Qo : Ko;
#pragma unroll
    for (int mi = 0; mi < 8; ++mi) {
      int m_base = bm + wm * 128 + mi * 16 + row_l;
#pragma unroll
      for (int j = 0; j < 4; ++j) {
        int n = bn + wn * 64 + j * 16 + col_l;
        float bv = bias[n];
        int h_ = n >> 6, hd_ = n & 63;
#pragma unroll
        for (int r = 0; r < 4; ++r) {
          int m = m_base + r;
          int b2 = m >> 11, s_ = m & 2047;
          out[(((size_t)(b2 * HH + h_) * SS) + s_) * HD + hd_] =
              f2bf((acc[mi][j][r] + bv) * scl);
        }
      }
    }
  } else {
    // V: transpose 256x256 C tile via LDS -> VTo[(b*HH+h)*HD+hd][s]
    unsigned int* Tt = (unsigned int*)&lds[0][0][0][0];  // 32768 dwords
#pragma unroll
    for (int mi = 0; mi < 8; ++mi) {
      int m2a = wm * 64 + mi * 8 + (l >> 4) * 2;  // dword index (m pair), even
#pragma unroll
      for (int j = 0; j < 4; ++j) {
        int n = wn * 64 + j * 16 + col_l;
        float bv = bias[bn + n];
        uint2 dd;
        dd.x = (unsigned)f2bf(acc[mi][j][0] + bv) |
               ((unsigned)f2bf(acc[mi][j][1] + bv) << 16);
        dd.y = (unsigned)f2bf(acc[mi][j][2] + bv) |
               ((unsigned)f2bf(acc[mi][j][3] + bv) << 16);
        *(uint2*)(Tt + n * 128 + (m2a ^ ((n & 7) << 2))) = dd;
      }
    }
    __syncthreads();
    const int srow0 = bm & 2047;
    const int n_r = t >> 1;
    const int half = t & 1;
    const int n_glob = bn + n_r;
    const int h_ = n_glob >> 6, hd_ = n_glob & 63;
    unsigned short* ob =
        VTo + ((size_t)((b_ * HH + h_) * HD + hd_)) * SS + srow0 + half * 128;
#pragma unroll
    for (int cp = 0; cp < 16; ++cp) {
      uint4 v = *(const uint4*)(Tt + n_r * 128 +
                                ((half * 64 + cp * 4) ^ ((n_r & 7) << 2)));
      *(uint4*)(ob + cp * 8) = v;
    }
  }
}

// ---------------------------------------------------------------------------
// MFMA flash attention v9: occupancy x2. R3 counters: Occ 32%, Mfma 28%,
// VALU 43%, LDS 64KB -> 2 blocks/CU was the limiter. v9 shrinks per-parity
// key subtiles 64->32 (K tile [32key x 64hd], V tile [64hd x 32key], 4 KB
// each) so dbuf x parity x {K,V} = 32 KB (+2 KB combine scratch) ->
// 4 blocks/CU = 32 waves/CU. Iterations double (32), per-iter MFMA halves;
// total MFMA/exp2/permlane work unchanged. Permlane algebra carries over:
// (lane g1g0, reg mt,p) -pl32-> (mt,g0|g1,p) -pl16-> (mt,g1|g0,p) = B-frag.
// V-read swizzle for 4-chunk rows: chunk = g ^ ((row>>1)&3) -> 2-way (free).
// ---------------------------------------------------------------------------
__global__ __launch_bounds__(512, 8) void flash_attn_mfma(
    const unsigned short* __restrict__ Q,   // [B,H,S,HD] bf16 (pre-scaled)
    const unsigned short* __restrict__ K,   // [B,H,S,HD] bf16
    const unsigned short* __restrict__ VT,  // [B,H,HD,S] bf16
    unsigned short* __restrict__ ctx) {     // [B,S,D] bf16
  const int bh = blockIdx.x;
  const int qt = blockIdx.y;
  const int b  = bh >> 4;
  const int h  = bh & 15;
  const int t  = threadIdx.x;
  const int w  = t >> 6;   // wave 0..7
  const int l  = t & 63;
  const int wg = w & 3;    // q sub-tile 0..3
  const int wh = w >> 2;   // key-subtile parity 0/1
  const int g  = l >> 4;   // lane group 0..3
  const int ln = l & 15;   // q index within n-tile

  const unsigned short* Qp = Q + ((size_t)bh * SS + (size_t)qt * 128 + wg * 32) * HD;
  const unsigned short* Kp = K + (size_t)bh * SS * HD;
  const unsigned short* Vp = VT + (size_t)bh * HD * SS;

  // [K=0/V=1][parity][dbuf][4 KB tile]; K tile [32key][64hd], V tile [64hd][32key]
  __shared__ __align__(16) unsigned short smem[2][2][2][2048];
  __shared__ __align__(16) float rred[4 * 64 * 2];  // 2 KB combine scratch

  // Q as B-operand fragments: qf[nt][kb], n=ln, k = kb*32 + g*8 + j
  bf16x8 qf[2][2];
#pragma unroll
  for (int nt = 0; nt < 2; ++nt)
#pragma unroll
    for (int kb = 0; kb < 2; ++kb)
      qf[nt][kb] = *(const bf16x8*)(Qp + (nt * 16 + ln) * HD + kb * 32 + g * 8);

  f32x4 o[2][4];
#pragma unroll
  for (int nt = 0; nt < 2; ++nt)
#pragma unroll
    for (int mt = 0; mt < 4; ++mt) o[nt][mt] = (f32x4)0.f;
  float rs[2] = {0.f, 0.f};

  // stage one 64-key group (both parities): K 512 chunks + V 512 chunks,
  // 1 chunk of each per thread. Wave-uniform LDS dest (base + lane*16).
  const int sp  = w >> 2;          // parity this wave stages
  const int sq  = w & 3;           // quarter within parity tile
  auto stage = [&](int kt, int db) {
    {  // K: chunk idx within parity tile = sq*64 + l; row=idx>>3, cc=idx&7
      const int idx = sq * 64 + l;
      const int row = idx >> 3, cc = idx & 7;
      const int gcc = cc ^ (row & 7);
      async_copy16(Kp + (size_t)(kt * 64 + sp * 32 + row) * HD + gcc * 8,
                   &smem[0][sp][db][sq * 512]);
    }
    {  // V: row=idx>>2 (hd), c2=idx&3 (key chunk), swz ^((row>>1)&3)
      const int idx = sq * 64 + l;
      const int row = idx >> 2, c2 = idx & 3;
      const int gc2 = c2 ^ ((row >> 1) & 3);
      async_copy16(Vp + (size_t)row * SS + kt * 64 + sp * 32 + gc2 * 8,
                   &smem[1][sp][db][sq * 512]);
    }
  };

  stage(0, 0);
  for (int kt = 0; kt < SS / 64; ++kt) {   // 32 iterations
    const int db = kt & 1;
    __syncthreads();  // drains vmcnt -> buf[db] ready; buf[db^1] free
    if (kt + 1 < SS / 64) stage(kt + 1, db ^ 1);

    const unsigned short* Kst = &smem[0][wh][db][0];
    const unsigned short* Vst = &smem[1][wh][db][0];

    // --- S^T = K Q^T : st[nt][mt][r] = S[key = mt*16+4g+r][q = nt*16+ln]
    f32x4 st[2][2];
#pragma unroll
    for (int nt = 0; nt < 2; ++nt)
#pragma unroll
      for (int mt = 0; mt < 2; ++mt) st[nt][mt] = (f32x4)0.f;
#pragma unroll
    for (int kb = 0; kb < 2; ++kb)
#pragma unroll
      for (int mt = 0; mt < 2; ++mt) {
        int row = mt * 16 + ln;
        bf16x8 ka = *(const bf16x8*)(&Kst[row * 64 + (((kb * 4 + g) ^ (row & 7)) * 8)]);
        st[0][mt] = __builtin_amdgcn_mfma_f32_16x16x32_bf16(ka, qf[0][kb], st[0][mt], 0, 0, 0);
        st[1][mt] = __builtin_amdgcn_mfma_f32_16x16x32_bf16(ka, qf[1][kb], st[1][mt], 0, 0, 0);
      }

    // --- p = exp2(s'); pack bf16 pairs in-register; permlane redistribute
    unsigned Sd[2][2][2];  // [nt][mt][p]: keys mt*16+4g+2p..+1, q=nt*16+ln
#pragma unroll
    for (int nt = 0; nt < 2; ++nt) {
#pragma unroll
      for (int mt = 0; mt < 2; ++mt) {
        float p0 = fast_exp2(st[nt][mt][0]);
        float p1 = fast_exp2(st[nt][mt][1]);
        float p2 = fast_exp2(st[nt][mt][2]);
        float p3 = fast_exp2(st[nt][mt][3]);
        Sd[nt][mt][0] = __builtin_amdgcn_perm(__float_as_uint(p1), __float_as_uint(p0),
                                              0x07060302u);  // lo=p0,hi=p1
        Sd[nt][mt][1] = __builtin_amdgcn_perm(__float_as_uint(p3), __float_as_uint(p2),
                                              0x07060302u);
        rs[nt] += (p0 + p1) + (p2 + p3);
      }
      // reg(mt) <-> lane-bit5, then reg <-> lane-bit4
#pragma unroll
      for (int p = 0; p < 2; ++p) pl32_swap(Sd[nt][0][p], Sd[nt][1][p]);
#pragma unroll
      for (int p = 0; p < 2; ++p) pl16_swap(Sd[nt][0][p], Sd[nt][1][p]);
    }
    // Now Sd[nt][i1][i0] = B-frag dword 2*i1+i0: keys g*8+2i..+1.

    // --- O^T += V^T P^T : P B-frags straight from registers (K-dim = 32)
    bf16x8 pbv[2];
#pragma unroll
    for (int nt = 0; nt < 2; ++nt) {
      union { unsigned u[4]; bf16x8 v; } cu;
      cu.u[0] = Sd[nt][0][0];
      cu.u[1] = Sd[nt][0][1];
      cu.u[2] = Sd[nt][1][0];
      cu.u[3] = Sd[nt][1][1];
      pbv[nt] = cu.v;
    }
#pragma unroll
    for (int mt = 0; mt < 4; ++mt) {
      int row = mt * 16 + ln;
      bf16x8 va = *(const bf16x8*)(&Vst[row * 32 + ((g ^ ((row >> 1) & 3)) * 8)]);
      o[0][mt] = __builtin_amdgcn_mfma_f32_16x16x32_bf16(va, pbv[0], o[0][mt], 0, 0, 0);
      o[1][mt] = __builtin_amdgcn_mfma_f32_16x16x32_bf16(va, pbv[1], o[1][mt], 0, 0, 0);
    }
  }

  // --- cross-parity combine: wh=1 waves dump partial o/rs to LDS, wh=0 adds.
  __syncthreads();  // all compute done; smem reusable as scratch
  {
    float* ored = (float*)&smem[0][0][0][0];  // 4 regions x 64 lanes x 32 f32 = 32 KB
    float* rb = ored + (wg * 64 + l) * 32;
    float* sb = rred + (wg * 64 + l) * 2;
    if (wh == 1) {
#pragma unroll
      for (int nt = 0; nt < 2; ++nt)
#pragma unroll
        for (int mt = 0; mt < 4; ++mt) {
          int idx = nt * 4 + mt;
          *(f32x4*)(rb + ((unsigned)(idx ^ (l & 7)) * 4)) = o[nt][mt];
        }
      sb[0] = rs[0];
      sb[1] = rs[1];
    }
    __syncthreads();
    if (wh == 1) return;
#pragma unroll
    for (int nt = 0; nt < 2; ++nt)
#pragma unroll
      for (int mt = 0; mt < 4; ++mt) {
        int idx = nt * 4 + mt;
        f32x4 pv = *(const f32x4*)(rb + ((unsigned)(idx ^ (l & 7)) * 4));
        o[nt][mt] += pv;
      }
    rs[0] += sb[0];
    rs[1] += sb[1];
  }

  // --- epilogue: reduce l over lane groups, normalize, store bf16 ctx
#pragma unroll
  for (int nt = 0; nt < 2; ++nt) {
    float lsum = rs[nt];
    lsum += __shfl_xor(lsum, 16, 64);
    lsum += __shfl_xor(lsum, 32, 64);
    float inv = 1.f / lsum;
    int srow = qt * 128 + wg * 32 + nt * 16 + ln;
    unsigned short* cb = ctx + (size_t)(b * SS + srow) * DD + h * HD;
#pragma unroll
    for (int mt = 0; mt < 4; ++mt) {
      ushort4 u4;
      u4.x = f2bf(o[nt][mt][0] * inv);
      u4.y = f2bf(o[nt][mt][1] * inv);
      u4.z = f2bf(o[nt][mt][2] * inv);
      u4.w = f2bf(o[nt][mt][3] * inv);
      *(ushort4*)(cb + mt * 16 + 4 * g) = u4;
    }
  }
}

// ---------------------------------------------------------------------------
extern "C" void kernel_launch(void* const* d_in, const int* in_sizes, int n_in,
                              void* d_out, int out_size, void* d_ws, size_t ws_size,
                              hipStream_t stream) {
  const float* x  = (const float*)d_in[0];
  const float* Wq = (const float*)d_in[1];
  const float* bq = (const float*)d_in[2];
  const float* Wk = (const float*)d_in[3];
  const float* bk = (const float*)d_in[4];
  const float* Wv = (const float*)d_in[5];
  const float* bv = (const float*)d_in[6];
  const float* Wo = (const float*)d_in[7];
  const float* bo = (const float*)d_in[8];
  float* out = (float*)d_out;

  const size_t ELEMS = (size_t)BB * SS * DD;  // 4,194,304
  char* ws = (char*)d_ws;
  unsigned short* xb   = (unsigned short*)ws;  ws += ELEMS * 2;
  unsigned short* WqT  = (unsigned short*)ws;  ws += (size_t)DD * DD * 2;
  unsigned short* WkT  = (unsigned short*)ws;  ws += (size_t)DD * DD * 2;
  unsigned short* WvT  = (unsigned short*)ws;  ws += (size_t)DD * DD * 2;
  unsigned short* WoT  = (unsigned short*)ws;  ws += (size_t)DD * DD * 2;
  unsigned short* Qb   = (unsigned short*)ws;  ws += ELEMS * 2;
  unsigned short* Kb   = (unsigned short*)ws;  ws += ELEMS * 2;
  unsigned short* VbT  = (unsigned short*)ws;  ws += ELEMS * 2;
  unsigned short* ctxb = (unsigned short*)ws;  ws += ELEMS * 2;

  prep_kernel<<<8192, 256, 0, stream>>>(x, xb, Wq, WqT, Wk, WkT, Wv, WvT, Wo, WoT);

  qkv_gemm_8ph<<<192, 512, 0, stream>>>(xb, WqT, WkT, WvT, bq, bk, bv,
                                        Qb, Kb, VbT);

  dim3 attn_grid(BB * HH, SS / 128);           // (32, 16) = 512 blocks
  flash_attn_mfma<<<attn_grid, 512, 0, stream>>>(Qb, Kb, VbT, ctxb);

  out_gemm_mfma<<<256, 256, 0, stream>>>(ctxb, WoT, bo, out);
}

// Round 6
// 200.936 us; speedup vs baseline: 1.5472x; 1.5472x over previous
//
#include <hip/hip_runtime.h>
#include <hip/hip_bf16.h>

#define BB 2
#define SS 2048
#define DD 1024
#define HH 16
#define HD 64

typedef __attribute__((ext_vector_type(8))) short bf16x8;
typedef __attribute__((ext_vector_type(4))) float f32x4;

// round-to-nearest-even f32 -> bf16 (inputs finite)
__device__ __forceinline__ unsigned short f2bf(float f) {
  unsigned int u = __float_as_uint(f);
  return (unsigned short)((u + 0x7FFFu + ((u >> 16) & 1u)) >> 16);
}

// 2^x via hardware v_exp_f32
__device__ __forceinline__ float fast_exp2(float x) {
#if __has_builtin(__builtin_amdgcn_exp2f)
  return __builtin_amdgcn_exp2f(x);
#else
  return __expf(x * 0.6931471805599453f);
#endif
}

__device__ __forceinline__ void async_copy16(const unsigned short* gp, unsigned short* lp) {
  __builtin_amdgcn_global_load_lds(
      (const __attribute__((address_space(1))) unsigned int*)gp,
      (__attribute__((address_space(3))) unsigned int*)lp, 16, 0, 0);
}

// gfx950 cross-lane register swaps (VALU, not DS pipe).
__device__ __forceinline__ void pl32_swap(unsigned& a, unsigned& b) {
#if __has_builtin(__builtin_amdgcn_permlane32_swap)
  auto r = __builtin_amdgcn_permlane32_swap(a, b, false, false);
  a = r[0];
  b = r[1];
#else
  asm volatile("v_permlane32_swap_b32 %0, %1" : "+v"(a), "+v"(b));
#endif
}
__device__ __forceinline__ void pl16_swap(unsigned& a, unsigned& b) {
#if __has_builtin(__builtin_amdgcn_permlane16_swap)
  auto r = __builtin_amdgcn_permlane16_swap(a, b, false, false);
  a = r[0];
  b = r[1];
#else
  asm volatile("v_permlane16_swap_b32 %0, %1" : "+v"(a), "+v"(b));
#endif
}

// ---------------------------------------------------------------------------
// Fused prep: blocks [0,4096) convert x -> bf16; blocks [4096,8192) transpose
// one of the 4 weight matrices (1024 32x32 tiles each) to bf16 [N][K].
// ---------------------------------------------------------------------------
__global__ __launch_bounds__(256) void prep_kernel(
    const float* __restrict__ x, unsigned short* __restrict__ xb,
    const float* __restrict__ W0, unsigned short* __restrict__ T0,
    const float* __restrict__ W1, unsigned short* __restrict__ T1,
    const float* __restrict__ W2, unsigned short* __restrict__ T2,
    const float* __restrict__ W3, unsigned short* __restrict__ T3) {
  const int blk = blockIdx.x;
  const int t = threadIdx.x;
  if (blk < 4096) {
    int i = blk * 1024 + t * 4;
    float4 v = *(const float4*)(x + i);
    ushort4 u;
    u.x = f2bf(v.x); u.y = f2bf(v.y); u.z = f2bf(v.z); u.w = f2bf(v.w);
    *(ushort4*)(xb + i) = u;
    return;
  }
  const int j = blk - 4096;
  const int jw = j >> 10;          // which weight
  const int tb = j & 1023;
  const float* W = jw == 0 ? W0 : (jw == 1 ? W1 : (jw == 2 ? W2 : W3));
  unsigned short* T = jw == 0 ? T0 : (jw == 1 ? T1 : (jw == 2 ? T2 : T3));
  __shared__ float tile[32][33];
  int k0 = (tb & 31) * 32, n0 = (tb >> 5) * 32;
  int c = t & 31, r0 = t >> 5;
#pragma unroll
  for (int i = 0; i < 4; ++i) {
    int r = r0 + i * 8;
    tile[r][c] = W[(size_t)(k0 + r) * DD + n0 + c];
  }
  __syncthreads();
#pragma unroll
  for (int i = 0; i < 4; ++i) {
    int r = r0 + i * 8;
    T[(size_t)(n0 + r) * DD + k0 + c] = f2bf(tile[c][r]);
  }
}

// ---------------------------------------------------------------------------
// bf16 MFMA GEMM core (m97 single-buffer, BK=32): D = A[M,K]@B^T[N,K] + bias
// STORE=0: fp32 out [M][DD]   (used by out-projection only)
// ---------------------------------------------------------------------------
template <int STORE>
__device__ __forceinline__ void gemm_core(
    const unsigned short* __restrict__ A, const unsigned short* __restrict__ BT,
    const float* __restrict__ bias, void* __restrict__ outp, float scale,
    int bm, int bn) {
  const int t = threadIdx.x;
  const int w = t >> 6;
  const int l = t & 63;
  const int wm = (w >> 1) * 64;
  const int wn = (w & 1) * 64;

  __shared__ __align__(16) unsigned short As[128 * 32];
  __shared__ __align__(16) unsigned short Bs[128 * 32];

  f32x4 acc[4][4];
#pragma unroll
  for (int i = 0; i < 4; ++i)
#pragma unroll
    for (int j = 0; j < 4; ++j) acc[i][j] = (f32x4)0.f;

  const int fr = l & 15;
  const int kg = (l >> 4) * 8;

  for (int k0 = 0; k0 < DD; k0 += 32) {
    __syncthreads();
#pragma unroll
    for (int c = 0; c < 2; ++c) {
      int e = (w * 2 + c) * 512 + l * 8;
      int row = e >> 5, kk = e & 31;
      async_copy16(A + (size_t)(bm + row) * DD + k0 + kk, As + (w * 2 + c) * 512);
      async_copy16(BT + (size_t)(bn + row) * DD + k0 + kk, Bs + (w * 2 + c) * 512);
    }
    __syncthreads();

    bf16x8 af[4], bfr[4];
#pragma unroll
    for (int i = 0; i < 4; ++i)
      af[i] = *(const bf16x8*)(As + (wm + i * 16 + fr) * 32 + kg);
#pragma unroll
    for (int j = 0; j < 4; ++j)
      bfr[j] = *(const bf16x8*)(Bs + (wn + j * 16 + fr) * 32 + kg);
#pragma unroll
    for (int i = 0; i < 4; ++i)
#pragma unroll
      for (int j = 0; j < 4; ++j)
        acc[i][j] = __builtin_amdgcn_mfma_f32_16x16x32_bf16(af[i], bfr[j], acc[i][j], 0, 0, 0);
  }

  const int col_l = l & 15;
  const int row_l = (l >> 4) * 4;

#pragma unroll
  for (int i = 0; i < 4; ++i) {
    int m_base = bm + wm + i * 16 + row_l;
#pragma unroll
    for (int j = 0; j < 4; ++j) {
      int n = bn + wn + j * 16 + col_l;
      float bv = bias[n];
      float* out = (float*)outp;
#pragma unroll
      for (int r = 0; r < 4; ++r)
        out[(size_t)(m_base + r) * DD + n] = acc[i][j][r] + bv;
    }
  }
}

// output projection, 256 blocks, XCD-swizzled (8 bn per bm on one XCD)
__global__ __launch_bounds__(256) void out_gemm_mfma(
    const unsigned short* __restrict__ A, const unsigned short* __restrict__ WoT,
    const float* __restrict__ bo, float* __restrict__ out) {
  const int i = blockIdx.x;
  const int xcd = i & 7;
  const int slot = i >> 3;            // 0..31
  const int bm = (xcd + 8 * (slot >> 3)) * 128;
  const int bn = (slot & 7) * 128;
  gemm_core<0>(A, WoT, bo, (void*)out, 1.0f, bm, bn);
}

// ---------------------------------------------------------------------------
// QKV projection, 8-phase 256x256xBK64 template (T2+T3+T4+T5). Verified R3:
// dropped out of the top-5 (was 54 us on the 128^2 2-barrier core).
// ---------------------------------------------------------------------------
#define QPHASE(DB, KH, MH, S, VM) do {                                        \
    bf16x8 af[4];                                                             \
    _Pragma("unroll")                                                         \
    for (int ii = 0; ii < 4; ++ii) {                                          \
      int row = wm * 128 + (MH) * 64 + ii * 16 + fr;                          \
      int kb = kg16 ^ ((row & 8) ? 32 : 0) ^ ((row & 4) ? 16 : 0);            \
      af[ii] = *(const bf16x8*)((const char*)&lds[0][DB][KH][0] + row * 64 + kb); \
    }                                                                         \
    if ((MH) == 0) {                                                          \
      _Pragma("unroll")                                                       \
      for (int j = 0; j < 4; ++j) {                                           \
        int row = wn * 64 + j * 16 + fr;                                      \
        int kb = kg16 ^ ((row & 8) ? 32 : 0) ^ ((row & 4) ? 16 : 0);          \
        bfr[j] = *(const bf16x8*)((const char*)&lds[1][DB][KH][0] + row * 64 + kb); \
      }                                                                       \
    }                                                                         \
    stage_half(S);                                                            \
    asm volatile("s_barrier" ::: "memory");                                   \
    __builtin_amdgcn_s_setprio(1);                                            \
    _Pragma("unroll")                                                         \
    for (int ii = 0; ii < 4; ++ii)                                            \
      _Pragma("unroll")                                                       \
      for (int j = 0; j < 4; ++j)                                             \
        acc[(MH) * 4 + ii][j] = __builtin_amdgcn_mfma_f32_16x16x32_bf16(      \
            af[ii], bfr[j], acc[(MH) * 4 + ii][j], 0, 0, 0);                  \
    __builtin_amdgcn_s_setprio(0);                                            \
    if ((VM) == 1) asm volatile("s_waitcnt vmcnt(4)" ::: "memory");           \
    if ((VM) == 2) asm volatile("s_waitcnt vmcnt(0)" ::: "memory");           \
    asm volatile("s_barrier" ::: "memory");                                   \
  } while (0)

__global__ __launch_bounds__(512, 2) void qkv_gemm_8ph(
    const unsigned short* __restrict__ A,
    const unsigned short* __restrict__ WqT, const unsigned short* __restrict__ WkT,
    const unsigned short* __restrict__ WvT,
    const float* __restrict__ bq, const float* __restrict__ bk,
    const float* __restrict__ bv,
    unsigned short* __restrict__ Qo, unsigned short* __restrict__ Ko,
    unsigned short* __restrict__ VTo) {
  const int i = blockIdx.x;
  const int xcd = i & 7;
  const int slot = i >> 3;              // 0..23
  const int bmi = xcd * 2 + (slot / 12);
  const int c = slot % 12;
  const int which = c >> 2;             // 0:Q 1:K 2:V
  const int bm = bmi * 256;
  const int bn = (c & 3) * 256;
  const unsigned short* BT = which == 0 ? WqT : (which == 1 ? WkT : WvT);
  const float* bias = which == 0 ? bq : (which == 1 ? bk : bv);

  const int t = threadIdx.x;
  const int w = t >> 6;
  const int l = t & 63;
  const int wm = w >> 2;        // 0..1 (M)
  const int wn = w & 3;         // 0..3 (N)
  const int fr = l & 15;
  const int kg16 = (l >> 4) * 16;   // byte offset of lane's k-group in 32k half

  // [mat A/B][dbuf][khalf][256 rows x 32 k] bf16, 128 KiB total
  __shared__ __align__(16) unsigned short lds[2][2][2][8192];

  f32x4 acc[8][4];
#pragma unroll
  for (int mi = 0; mi < 8; ++mi)
#pragma unroll
    for (int j = 0; j < 4; ++j) acc[mi][j] = (f32x4)0.f;

  // stage half-tile s (s = 4*T + {0:A_k0,1:B_k0,2:A_k1,3:B_k1}); 2 loads/thr
  auto stage_half = [&](int s) {
    if (s >= 64) return;
    const int Ts = s >> 2;
    const int db = Ts & 1;
    const int typ = s & 3;
    const int kh = typ >> 1;
    const int isB = typ & 1;
    const unsigned short* src = isB ? BT : A;
    const int rbase = isB ? bn : bm;
    unsigned short* dstbase = &lds[isB][db][kh][0];
    const int k0 = Ts * 64 + kh * 32;
#pragma unroll
    for (int j = 0; j < 2; ++j) {
      int cc = (w * 2 + j) * 64 + l;    // 16B chunk 0..1023
      int row = cc >> 2;
      int ke = ((cc & 3) * 8) ^ ((row & 8) ? 16 : 0) ^ ((row & 4) ? 8 : 0);
      async_copy16(src + (size_t)(rbase + row) * DD + k0 + ke,
                   dstbase + (w * 2 + j) * 512);
    }
  };

  bf16x8 bfr[4];

  // prologue: tile0 (4 halves) + tile1 first 2 halves; wait tile0 landed
  for (int s = 0; s < 6; ++s) stage_half(s);
  asm volatile("s_waitcnt vmcnt(4)" ::: "memory");
  asm volatile("s_barrier" ::: "memory");

  for (int T = 0; T < 14; ++T) {
    const int db = T & 1;
    const int sb = 4 * T + 6;
    QPHASE(db, 0, 0, sb + 0, 0);
    QPHASE(db, 0, 1, sb + 1, 0);
    QPHASE(db, 1, 0, sb + 2, 0);
    QPHASE(db, 1, 1, sb + 3, 1);      // boundary: vmcnt(4)
  }
  // T = 14 (db 0): stages s=62,63 then exhausted; final drain at boundary
  QPHASE(0, 0, 0, 62, 0);
  QPHASE(0, 0, 1, 63, 0);
  QPHASE(0, 1, 0, 64, 0);
  QPHASE(0, 1, 1, 64, 2);             // vmcnt(0): everything landed
  // T = 15 (db 1): no staging, no waits needed
  QPHASE(1, 0, 0, 64, 0);
  QPHASE(1, 0, 1, 64, 0);
  QPHASE(1, 1, 0, 64, 0);
  QPHASE(1, 1, 1, 64, 0);

  const int col_l = l & 15;
  const int row_l = (l >> 4) * 4;
  const int b_ = bm >> 11;

  if (which != 2) {
    // Q/K: bf16 out [B,H,S,HD], scaled
    const float scl = which == 0 ? 0.18033688011112042f : 1.0f;
    unsigned short* out = which == 0 ? Qo : Ko;
#pragma unroll
    for (int mi = 0; mi < 8; ++mi) {
      int m_base = bm + wm * 128 + mi * 16 + row_l;
#pragma unroll
      for (int j = 0; j < 4; ++j) {
        int n = bn + wn * 64 + j * 16 + col_l;
        float bv = bias[n];
        int h_ = n >> 6, hd_ = n & 63;
#pragma unroll
        for (int r = 0; r < 4; ++r) {
          int m = m_base + r;
          int b2 = m >> 11, s_ = m & 2047;
          out[(((size_t)(b2 * HH + h_) * SS) + s_) * HD + hd_] =
              f2bf((acc[mi][j][r] + bv) * scl);
        }
      }
    }
  } else {
    // V: transpose 256x256 C tile via LDS -> VTo[(b*HH+h)*HD+hd][s]
    unsigned int* Tt = (unsigned int*)&lds[0][0][0][0];  // 32768 dwords
#pragma unroll
    for (int mi = 0; mi < 8; ++mi) {
      int m2a = wm * 64 + mi * 8 + (l >> 4) * 2;  // dword index (m pair), even
#pragma unroll
      for (int j = 0; j < 4; ++j) {
        int n = wn * 64 + j * 16 + col_l;
        float bv = bias[bn + n];
        uint2 dd;
        dd.x = (unsigned)f2bf(acc[mi][j][0] + bv) |
               ((unsigned)f2bf(acc[mi][j][1] + bv) << 16);
        dd.y = (unsigned)f2bf(acc[mi][j][2] + bv) |
               ((unsigned)f2bf(acc[mi][j][3] + bv) << 16);
        *(uint2*)(Tt + n * 128 + (m2a ^ ((n & 7) << 2))) = dd;
      }
    }
    __syncthreads();
    const int srow0 = bm & 2047;
    const int n_r = t >> 1;
    const int half = t & 1;
    const int n_glob = bn + n_r;
    const int h_ = n_glob >> 6, hd_ = n_glob & 63;
    unsigned short* ob =
        VTo + ((size_t)((b_ * HH + h_) * HD + hd_)) * SS + srow0 + half * 128;
#pragma unroll
    for (int cp = 0; cp < 16; ++cp) {
      uint4 v = *(const uint4*)(Tt + n_r * 128 +
                                ((half * 64 + cp * 4) ^ ((n_r & 7) << 2)));
      *(uint4*)(ob + cp * 8) = v;
    }
  }
}

// ---------------------------------------------------------------------------
// MFMA flash attention v10. v9 post-mortem: __launch_bounds__ 2nd arg is
// BLOCKS/CU (v9's (512,8) -> 32-VGPR cap -> spill hell: VGPR=32, 284 MB
// scratch writes). v10: (512,4) -> 64-VGPR cap (v8 proved this compiles
// clean), and per-wave state HALVED so ~50 regs peak genuinely fits:
// each wave owns 16 q-rows (not 32). 8 waves = 4 q-subtiles x 2 key
// parities over a 64-q-row block; grid (32 qt, 32 bh) = 1024 blocks =
// exactly 4 blocks/CU; LDS 33 KB -> occupancy 32 waves/CU (2x v8).
// qt-fastest grid ordering: consecutive blocks share bh -> K/V L2
// locality per XCD. Stage/swizzle/permlane logic verbatim from v9
// (correctness-verified); only the nt dimension is dropped.
// ---------------------------------------------------------------------------
__global__ __launch_bounds__(512, 4) void flash_attn_mfma(
    const unsigned short* __restrict__ Q,   // [B,H,S,HD] bf16 (pre-scaled)
    const unsigned short* __restrict__ K,   // [B,H,S,HD] bf16
    const unsigned short* __restrict__ VT,  // [B,H,HD,S] bf16
    unsigned short* __restrict__ ctx) {     // [B,S,D] bf16
  const int qt = blockIdx.x;   // 64-row q tile
  const int bh = blockIdx.y;
  const int b  = bh >> 4;
  const int h  = bh & 15;
  const int t  = threadIdx.x;
  const int w  = t >> 6;   // wave 0..7
  const int l  = t & 63;
  const int wg = w & 3;    // q sub-tile 0..3 (16 rows each)
  const int wh = w >> 2;   // key-subtile parity 0/1
  const int g  = l >> 4;   // lane group 0..3
  const int ln = l & 15;   // q index within 16-row tile

  const unsigned short* Qp = Q + ((size_t)bh * SS + (size_t)qt * 64 + wg * 16) * HD;
  const unsigned short* Kp = K + (size_t)bh * SS * HD;
  const unsigned short* Vp = VT + (size_t)bh * HD * SS;

  // [K=0/V=1][parity][dbuf][4 KB tile]; K tile [32key][64hd], V tile [64hd][32key]
  __shared__ __align__(16) unsigned short smem[2][2][2][2048];
  __shared__ __align__(16) float rred[4 * 64];  // 1 KB combine scratch (rs)

  // Q as B-operand fragments: qf[kb], n=ln, k = kb*32 + g*8 + j
  bf16x8 qf[2];
#pragma unroll
  for (int kb = 0; kb < 2; ++kb)
    qf[kb] = *(const bf16x8*)(Qp + ln * HD + kb * 32 + g * 8);

  f32x4 o[4];
#pragma unroll
  for (int mt = 0; mt < 4; ++mt) o[mt] = (f32x4)0.f;
  float rs = 0.f;

  // stage one 64-key group (both parities): K 512 chunks + V 512 chunks,
  // 1 chunk of each per thread. Wave-uniform LDS dest (base + lane*16).
  const int sp  = w >> 2;          // parity this wave stages
  const int sq  = w & 3;           // quarter within parity tile
  auto stage = [&](int kt, int db) {
    {  // K: chunk idx within parity tile = sq*64 + l; row=idx>>3, cc=idx&7
      const int idx = sq * 64 + l;
      const int row = idx >> 3, cc = idx & 7;
      const int gcc = cc ^ (row & 7);
      async_copy16(Kp + (size_t)(kt * 64 + sp * 32 + row) * HD + gcc * 8,
                   &smem[0][sp][db][sq * 512]);
    }
    {  // V: row=idx>>2 (hd), c2=idx&3 (key chunk), swz ^((row>>1)&3)
      const int idx = sq * 64 + l;
      const int row = idx >> 2, c2 = idx & 3;
      const int gc2 = c2 ^ ((row >> 1) & 3);
      async_copy16(Vp + (size_t)row * SS + kt * 64 + sp * 32 + gc2 * 8,
                   &smem[1][sp][db][sq * 512]);
    }
  };

  stage(0, 0);
  for (int kt = 0; kt < SS / 64; ++kt) {   // 32 iterations
    const int db = kt & 1;
    __syncthreads();  // drains vmcnt -> buf[db] ready; buf[db^1] free
    if (kt + 1 < SS / 64) stage(kt + 1, db ^ 1);

    const unsigned short* Kst = &smem[0][wh][db][0];
    const unsigned short* Vst = &smem[1][wh][db][0];

    // --- S^T = K Q^T : st[mt][r] = S[key = mt*16+4g+r][q = ln]
    f32x4 st[2];
#pragma unroll
    for (int mt = 0; mt < 2; ++mt) st[mt] = (f32x4)0.f;
#pragma unroll
    for (int kb = 0; kb < 2; ++kb)
#pragma unroll
      for (int mt = 0; mt < 2; ++mt) {
        int row = mt * 16 + ln;
        bf16x8 ka = *(const bf16x8*)(&Kst[row * 64 + (((kb * 4 + g) ^ (row & 7)) * 8)]);
        st[mt] = __builtin_amdgcn_mfma_f32_16x16x32_bf16(ka, qf[kb], st[mt], 0, 0, 0);
      }

    // --- p = exp2(s'); pack bf16 pairs in-register; permlane redistribute
    unsigned Sd[2][2];  // [mt][p]: keys mt*16+4g+2p..+1, q=ln
#pragma unroll
    for (int mt = 0; mt < 2; ++mt) {
      float p0 = fast_exp2(st[mt][0]);
      float p1 = fast_exp2(st[mt][1]);
      float p2 = fast_exp2(st[mt][2]);
      float p3 = fast_exp2(st[mt][3]);
      Sd[mt][0] = __builtin_amdgcn_perm(__float_as_uint(p1), __float_as_uint(p0),
                                        0x07060302u);  // lo=p0,hi=p1
      Sd[mt][1] = __builtin_amdgcn_perm(__float_as_uint(p3), __float_as_uint(p2),
                                        0x07060302u);
      rs += (p0 + p1) + (p2 + p3);
    }
    // reg(mt) <-> lane-bit5, then reg <-> lane-bit4
#pragma unroll
    for (int p = 0; p < 2; ++p) pl32_swap(Sd[0][p], Sd[1][p]);
#pragma unroll
    for (int p = 0; p < 2; ++p) pl16_swap(Sd[0][p], Sd[1][p]);
    // Now Sd[i1][i0] = B-frag dword 2*i1+i0: keys g*8+2i..+1.

    // --- O^T += V^T P^T : P B-frag straight from registers (K-dim = 32)
    bf16x8 pbv;
    {
      union { unsigned u[4]; bf16x8 v; } cu;
      cu.u[0] = Sd[0][0];
      cu.u[1] = Sd[0][1];
      cu.u[2] = Sd[1][0];
      cu.u[3] = Sd[1][1];
      pbv = cu.v;
    }
#pragma unroll
    for (int mt = 0; mt < 4; ++mt) {
      int row = mt * 16 + ln;
      bf16x8 va = *(const bf16x8*)(&Vst[row * 32 + ((g ^ ((row >> 1) & 3)) * 8)]);
      o[mt] = __builtin_amdgcn_mfma_f32_16x16x32_bf16(va, pbv, o[mt], 0, 0, 0);
    }
  }

  // --- cross-parity combine: wh=1 waves dump partial o/rs to LDS, wh=0 adds.
  __syncthreads();  // all compute done; smem reusable as scratch
  {
    float* ored = (float*)&smem[0][0][0][0];  // 4 regions x 64 lanes x 16 f32 = 16 KB
    float* rb = ored + (wg * 64 + l) * 16;
    float* sb = rred + wg * 64 + l;
    if (wh == 1) {
#pragma unroll
      for (int mt = 0; mt < 4; ++mt)
        *(f32x4*)(rb + ((unsigned)(mt ^ (l & 3)) * 4)) = o[mt];
      sb[0] = rs;
    }
    __syncthreads();
    if (wh == 1) return;
#pragma unroll
    for (int mt = 0; mt < 4; ++mt) {
      f32x4 pv = *(const f32x4*)(rb + ((unsigned)(mt ^ (l & 3)) * 4));
      o[mt] += pv;
    }
    rs += sb[0];
  }

  // --- epilogue: reduce rs over lane groups, normalize, store bf16 ctx
  {
    float lsum = rs;
    lsum += __shfl_xor(lsum, 16, 64);
    lsum += __shfl_xor(lsum, 32, 64);
    float inv = 1.f / lsum;
    int srow = qt * 64 + wg * 16 + ln;
    unsigned short* cb = ctx + (size_t)(b * SS + srow) * DD + h * HD;
#pragma unroll
    for (int mt = 0; mt < 4; ++mt) {
      ushort4 u4;
      u4.x = f2bf(o[mt][0] * inv);
      u4.y = f2bf(o[mt][1] * inv);
      u4.z = f2bf(o[mt][2] * inv);
      u4.w = f2bf(o[mt][3] * inv);
      *(ushort4*)(cb + mt * 16 + 4 * g) = u4;
    }
  }
}

// ---------------------------------------------------------------------------
extern "C" void kernel_launch(void* const* d_in, const int* in_sizes, int n_in,
                              void* d_out, int out_size, void* d_ws, size_t ws_size,
                              hipStream_t stream) {
  const float* x  = (const float*)d_in[0];
  const float* Wq = (const float*)d_in[1];
  const float* bq = (const float*)d_in[2];
  const float* Wk = (const float*)d_in[3];
  const float* bk = (const float*)d_in[4];
  const float* Wv = (const float*)d_in[5];
  const float* bv = (const float*)d_in[6];
  const float* Wo = (const float*)d_in[7];
  const float* bo = (const float*)d_in[8];
  float* out = (float*)d_out;

  const size_t ELEMS = (size_t)BB * SS * DD;  // 4,194,304
  char* ws = (char*)d_ws;
  unsigned short* xb   = (unsigned short*)ws;  ws += ELEMS * 2;
  unsigned short* WqT  = (unsigned short*)ws;  ws += (size_t)DD * DD * 2;
  unsigned short* WkT  = (unsigned short*)ws;  ws += (size_t)DD * DD * 2;
  unsigned short* WvT  = (unsigned short*)ws;  ws += (size_t)DD * DD * 2;
  unsigned short* WoT  = (unsigned short*)ws;  ws += (size_t)DD * DD * 2;
  unsigned short* Qb   = (unsigned short*)ws;  ws += ELEMS * 2;
  unsigned short* Kb   = (unsigned short*)ws;  ws += ELEMS * 2;
  unsigned short* VbT  = (unsigned short*)ws;  ws += ELEMS * 2;
  unsigned short* ctxb = (unsigned short*)ws;  ws += ELEMS * 2;

  prep_kernel<<<8192, 256, 0, stream>>>(x, xb, Wq, WqT, Wk, WkT, Wv, WvT, Wo, WoT);

  qkv_gemm_8ph<<<192, 512, 0, stream>>>(xb, WqT, WkT, WvT, bq, bk, bv,
                                        Qb, Kb, VbT);

  dim3 attn_grid(SS / 64, BB * HH);            // (32, 32) = 1024 blocks
  flash_attn_mfma<<<attn_grid, 512, 0, stream>>>(Qb, Kb, VbT, ctxb);

  out_gemm_mfma<<<256, 256, 0, stream>>>(ctxb, WoT, bo, out);
}

// Round 7
// 198.296 us; speedup vs baseline: 1.5678x; 1.0133x over previous
//
#include <hip/hip_runtime.h>
#include <hip/hip_bf16.h>

#define BB 2
#define SS 2048
#define DD 1024
#define HH 16
#define HD 64

typedef __attribute__((ext_vector_type(8))) short bf16x8;
typedef __attribute__((ext_vector_type(4))) float f32x4;

// round-to-nearest-even f32 -> bf16 (inputs finite)
__device__ __forceinline__ unsigned short f2bf(float f) {
  unsigned int u = __float_as_uint(f);
  return (unsigned short)((u + 0x7FFFu + ((u >> 16) & 1u)) >> 16);
}

// 2^x via hardware v_exp_f32
__device__ __forceinline__ float fast_exp2(float x) {
#if __has_builtin(__builtin_amdgcn_exp2f)
  return __builtin_amdgcn_exp2f(x);
#else
  return __expf(x * 0.6931471805599453f);
#endif
}

__device__ __forceinline__ void async_copy16(const unsigned short* gp, unsigned short* lp) {
  __builtin_amdgcn_global_load_lds(
      (const __attribute__((address_space(1))) unsigned int*)gp,
      (__attribute__((address_space(3))) unsigned int*)lp, 16, 0, 0);
}

// gfx950 cross-lane register swaps (VALU, not DS pipe).
__device__ __forceinline__ void pl32_swap(unsigned& a, unsigned& b) {
#if __has_builtin(__builtin_amdgcn_permlane32_swap)
  auto r = __builtin_amdgcn_permlane32_swap(a, b, false, false);
  a = r[0];
  b = r[1];
#else
  asm volatile("v_permlane32_swap_b32 %0, %1" : "+v"(a), "+v"(b));
#endif
}
__device__ __forceinline__ void pl16_swap(unsigned& a, unsigned& b) {
#if __has_builtin(__builtin_amdgcn_permlane16_swap)
  auto r = __builtin_amdgcn_permlane16_swap(a, b, false, false);
  a = r[0];
  b = r[1];
#else
  asm volatile("v_permlane16_swap_b32 %0, %1" : "+v"(a), "+v"(b));
#endif
}

// ---------------------------------------------------------------------------
// Fused prep: blocks [0,4096) convert x -> bf16; blocks [4096,8192) transpose
// one of the 4 weight matrices (1024 32x32 tiles each) to bf16 [N][K].
// ---------------------------------------------------------------------------
__global__ __launch_bounds__(256) void prep_kernel(
    const float* __restrict__ x, unsigned short* __restrict__ xb,
    const float* __restrict__ W0, unsigned short* __restrict__ T0,
    const float* __restrict__ W1, unsigned short* __restrict__ T1,
    const float* __restrict__ W2, unsigned short* __restrict__ T2,
    const float* __restrict__ W3, unsigned short* __restrict__ T3) {
  const int blk = blockIdx.x;
  const int t = threadIdx.x;
  if (blk < 4096) {
    int i = blk * 1024 + t * 4;
    float4 v = *(const float4*)(x + i);
    ushort4 u;
    u.x = f2bf(v.x); u.y = f2bf(v.y); u.z = f2bf(v.z); u.w = f2bf(v.w);
    *(ushort4*)(xb + i) = u;
    return;
  }
  const int j = blk - 4096;
  const int jw = j >> 10;          // which weight
  const int tb = j & 1023;
  const float* W = jw == 0 ? W0 : (jw == 1 ? W1 : (jw == 2 ? W2 : W3));
  unsigned short* T = jw == 0 ? T0 : (jw == 1 ? T1 : (jw == 2 ? T2 : T3));
  __shared__ float tile[32][33];
  int k0 = (tb & 31) * 32, n0 = (tb >> 5) * 32;
  int c = t & 31, r0 = t >> 5;
#pragma unroll
  for (int i = 0; i < 4; ++i) {
    int r = r0 + i * 8;
    tile[r][c] = W[(size_t)(k0 + r) * DD + n0 + c];
  }
  __syncthreads();
#pragma unroll
  for (int i = 0; i < 4; ++i) {
    int r = r0 + i * 8;
    T[(size_t)(n0 + r) * DD + k0 + c] = f2bf(tile[c][r]);
  }
}

// ---------------------------------------------------------------------------
// bf16 MFMA GEMM core (m97 single-buffer, BK=32): D = A[M,K]@B^T[N,K] + bias
// STORE=0: fp32 out [M][DD]   (used by out-projection only)
// ---------------------------------------------------------------------------
template <int STORE>
__device__ __forceinline__ void gemm_core(
    const unsigned short* __restrict__ A, const unsigned short* __restrict__ BT,
    const float* __restrict__ bias, void* __restrict__ outp, float scale,
    int bm, int bn) {
  const int t = threadIdx.x;
  const int w = t >> 6;
  const int l = t & 63;
  const int wm = (w >> 1) * 64;
  const int wn = (w & 1) * 64;

  __shared__ __align__(16) unsigned short As[128 * 32];
  __shared__ __align__(16) unsigned short Bs[128 * 32];

  f32x4 acc[4][4];
#pragma unroll
  for (int i = 0; i < 4; ++i)
#pragma unroll
    for (int j = 0; j < 4; ++j) acc[i][j] = (f32x4)0.f;

  const int fr = l & 15;
  const int kg = (l >> 4) * 8;

  for (int k0 = 0; k0 < DD; k0 += 32) {
    __syncthreads();
#pragma unroll
    for (int c = 0; c < 2; ++c) {
      int e = (w * 2 + c) * 512 + l * 8;
      int row = e >> 5, kk = e & 31;
      async_copy16(A + (size_t)(bm + row) * DD + k0 + kk, As + (w * 2 + c) * 512);
      async_copy16(BT + (size_t)(bn + row) * DD + k0 + kk, Bs + (w * 2 + c) * 512);
    }
    __syncthreads();

    bf16x8 af[4], bfr[4];
#pragma unroll
    for (int i = 0; i < 4; ++i)
      af[i] = *(const bf16x8*)(As + (wm + i * 16 + fr) * 32 + kg);
#pragma unroll
    for (int j = 0; j < 4; ++j)
      bfr[j] = *(const bf16x8*)(Bs + (wn + j * 16 + fr) * 32 + kg);
#pragma unroll
    for (int i = 0; i < 4; ++i)
#pragma unroll
      for (int j = 0; j < 4; ++j)
        acc[i][j] = __builtin_amdgcn_mfma_f32_16x16x32_bf16(af[i], bfr[j], acc[i][j], 0, 0, 0);
  }

  const int col_l = l & 15;
  const int row_l = (l >> 4) * 4;

#pragma unroll
  for (int i = 0; i < 4; ++i) {
    int m_base = bm + wm + i * 16 + row_l;
#pragma unroll
    for (int j = 0; j < 4; ++j) {
      int n = bn + wn + j * 16 + col_l;
      float bv = bias[n];
      float* out = (float*)outp;
#pragma unroll
      for (int r = 0; r < 4; ++r)
        out[(size_t)(m_base + r) * DD + n] = acc[i][j][r] + bv;
    }
  }
}

// output projection, 256 blocks, XCD-swizzled (8 bn per bm on one XCD)
__global__ __launch_bounds__(256) void out_gemm_mfma(
    const unsigned short* __restrict__ A, const unsigned short* __restrict__ WoT,
    const float* __restrict__ bo, float* __restrict__ out) {
  const int i = blockIdx.x;
  const int xcd = i & 7;
  const int slot = i >> 3;            // 0..31
  const int bm = (xcd + 8 * (slot >> 3)) * 128;
  const int bn = (slot & 7) * 128;
  gemm_core<0>(A, WoT, bo, (void*)out, 1.0f, bm, bn);
}

// ---------------------------------------------------------------------------
// QKV projection, 8-phase 256x256xBK64 template (T2+T3+T4+T5). Verified R3.
// ---------------------------------------------------------------------------
#define QPHASE(DB, KH, MH, S, VM) do {                                        \
    bf16x8 af[4];                                                             \
    _Pragma("unroll")                                                         \
    for (int ii = 0; ii < 4; ++ii) {                                          \
      int row = wm * 128 + (MH) * 64 + ii * 16 + fr;                          \
      int kb = kg16 ^ ((row & 8) ? 32 : 0) ^ ((row & 4) ? 16 : 0);            \
      af[ii] = *(const bf16x8*)((const char*)&lds[0][DB][KH][0] + row * 64 + kb); \
    }                                                                         \
    if ((MH) == 0) {                                                          \
      _Pragma("unroll")                                                       \
      for (int j = 0; j < 4; ++j) {                                           \
        int row = wn * 64 + j * 16 + fr;                                      \
        int kb = kg16 ^ ((row & 8) ? 32 : 0) ^ ((row & 4) ? 16 : 0);          \
        bfr[j] = *(const bf16x8*)((const char*)&lds[1][DB][KH][0] + row * 64 + kb); \
      }                                                                       \
    }                                                                         \
    stage_half(S);                                                            \
    asm volatile("s_barrier" ::: "memory");                                   \
    __builtin_amdgcn_s_setprio(1);                                            \
    _Pragma("unroll")                                                         \
    for (int ii = 0; ii < 4; ++ii)                                            \
      _Pragma("unroll")                                                       \
      for (int j = 0; j < 4; ++j)                                             \
        acc[(MH) * 4 + ii][j] = __builtin_amdgcn_mfma_f32_16x16x32_bf16(      \
            af[ii], bfr[j], acc[(MH) * 4 + ii][j], 0, 0, 0);                  \
    __builtin_amdgcn_s_setprio(0);                                            \
    if ((VM) == 1) asm volatile("s_waitcnt vmcnt(4)" ::: "memory");           \
    if ((VM) == 2) asm volatile("s_waitcnt vmcnt(0)" ::: "memory");           \
    asm volatile("s_barrier" ::: "memory");                                   \
  } while (0)

__global__ __launch_bounds__(512, 2) void qkv_gemm_8ph(
    const unsigned short* __restrict__ A,
    const unsigned short* __restrict__ WqT, const unsigned short* __restrict__ WkT,
    const unsigned short* __restrict__ WvT,
    const float* __restrict__ bq, const float* __restrict__ bk,
    const float* __restrict__ bv,
    unsigned short* __restrict__ Qo, unsigned short* __restrict__ Ko,
    unsigned short* __restrict__ VTo) {
  const int i = blockIdx.x;
  const int xcd = i & 7;
  const int slot = i >> 3;              // 0..23
  const int bmi = xcd * 2 + (slot / 12);
  const int c = slot % 12;
  const int which = c >> 2;             // 0:Q 1:K 2:V
  const int bm = bmi * 256;
  const int bn = (c & 3) * 256;
  const unsigned short* BT = which == 0 ? WqT : (which == 1 ? WkT : WvT);
  const float* bias = which == 0 ? bq : (which == 1 ? bk : bv);

  const int t = threadIdx.x;
  const int w = t >> 6;
  const int l = t & 63;
  const int wm = w >> 2;        // 0..1 (M)
  const int wn = w & 3;         // 0..3 (N)
  const int fr = l & 15;
  const int kg16 = (l >> 4) * 16;   // byte offset of lane's k-group in 32k half

  // [mat A/B][dbuf][khalf][256 rows x 32 k] bf16, 128 KiB total
  __shared__ __align__(16) unsigned short lds[2][2][2][8192];

  f32x4 acc[8][4];
#pragma unroll
  for (int mi = 0; mi < 8; ++mi)
#pragma unroll
    for (int j = 0; j < 4; ++j) acc[mi][j] = (f32x4)0.f;

  // stage half-tile s (s = 4*T + {0:A_k0,1:B_k0,2:A_k1,3:B_k1}); 2 loads/thr
  auto stage_half = [&](int s) {
    if (s >= 64) return;
    const int Ts = s >> 2;
    const int db = Ts & 1;
    const int typ = s & 3;
    const int kh = typ >> 1;
    const int isB = typ & 1;
    const unsigned short* src = isB ? BT : A;
    const int rbase = isB ? bn : bm;
    unsigned short* dstbase = &lds[isB][db][kh][0];
    const int k0 = Ts * 64 + kh * 32;
#pragma unroll
    for (int j = 0; j < 2; ++j) {
      int cc = (w * 2 + j) * 64 + l;    // 16B chunk 0..1023
      int row = cc >> 2;
      int ke = ((cc & 3) * 8) ^ ((row & 8) ? 16 : 0) ^ ((row & 4) ? 8 : 0);
      async_copy16(src + (size_t)(rbase + row) * DD + k0 + ke,
                   dstbase + (w * 2 + j) * 512);
    }
  };

  bf16x8 bfr[4];

  // prologue: tile0 (4 halves) + tile1 first 2 halves; wait tile0 landed
  for (int s = 0; s < 6; ++s) stage_half(s);
  asm volatile("s_waitcnt vmcnt(4)" ::: "memory");
  asm volatile("s_barrier" ::: "memory");

  for (int T = 0; T < 14; ++T) {
    const int db = T & 1;
    const int sb = 4 * T + 6;
    QPHASE(db, 0, 0, sb + 0, 0);
    QPHASE(db, 0, 1, sb + 1, 0);
    QPHASE(db, 1, 0, sb + 2, 0);
    QPHASE(db, 1, 1, sb + 3, 1);      // boundary: vmcnt(4)
  }
  // T = 14 (db 0): stages s=62,63 then exhausted; final drain at boundary
  QPHASE(0, 0, 0, 62, 0);
  QPHASE(0, 0, 1, 63, 0);
  QPHASE(0, 1, 0, 64, 0);
  QPHASE(0, 1, 1, 64, 2);             // vmcnt(0): everything landed
  // T = 15 (db 1): no staging, no waits needed
  QPHASE(1, 0, 0, 64, 0);
  QPHASE(1, 0, 1, 64, 0);
  QPHASE(1, 1, 0, 64, 0);
  QPHASE(1, 1, 1, 64, 0);

  const int col_l = l & 15;
  const int row_l = (l >> 4) * 4;
  const int b_ = bm >> 11;

  if (which != 2) {
    // Q/K: bf16 out [B,H,S,HD], scaled
    const float scl = which == 0 ? 0.18033688011112042f : 1.0f;
    unsigned short* out = which == 0 ? Qo : Ko;
#pragma unroll
    for (int mi = 0; mi < 8; ++mi) {
      int m_base = bm + wm * 128 + mi * 16 + row_l;
#pragma unroll
      for (int j = 0; j < 4; ++j) {
        int n = bn + wn * 64 + j * 16 + col_l;
        float bv = bias[n];
        int h_ = n >> 6, hd_ = n & 63;
#pragma unroll
        for (int r = 0; r < 4; ++r) {
          int m = m_base + r;
          int b2 = m >> 11, s_ = m & 2047;
          out[(((size_t)(b2 * HH + h_) * SS) + s_) * HD + hd_] =
              f2bf((acc[mi][j][r] + bv) * scl);
        }
      }
    }
  } else {
    // V: transpose 256x256 C tile via LDS -> VTo[(b*HH+h)*HD+hd][s]
    unsigned int* Tt = (unsigned int*)&lds[0][0][0][0];  // 32768 dwords
#pragma unroll
    for (int mi = 0; mi < 8; ++mi) {
      int m2a = wm * 64 + mi * 8 + (l >> 4) * 2;  // dword index (m pair), even
#pragma unroll
      for (int j = 0; j < 4; ++j) {
        int n = wn * 64 + j * 16 + col_l;
        float bv = bias[bn + n];
        uint2 dd;
        dd.x = (unsigned)f2bf(acc[mi][j][0] + bv) |
               ((unsigned)f2bf(acc[mi][j][1] + bv) << 16);
        dd.y = (unsigned)f2bf(acc[mi][j][2] + bv) |
               ((unsigned)f2bf(acc[mi][j][3] + bv) << 16);
        *(uint2*)(Tt + n * 128 + (m2a ^ ((n & 7) << 2))) = dd;
      }
    }
    __syncthreads();
    const int srow0 = bm & 2047;
    const int n_r = t >> 1;
    const int half = t & 1;
    const int n_glob = bn + n_r;
    const int h_ = n_glob >> 6, hd_ = n_glob & 63;
    unsigned short* ob =
        VTo + ((size_t)((b_ * HH + h_) * HD + hd_)) * SS + srow0 + half * 128;
#pragma unroll
    for (int cp = 0; cp < 16; ++cp) {
      uint4 v = *(const uint4*)(Tt + n_r * 128 +
                                ((half * 64 + cp * 4) ^ ((n_r & 7) << 2)));
      *(uint4*)(ob + cp * 8) = v;
    }
  }
}

// ---------------------------------------------------------------------------
// MFMA flash attention v11 = v10 + grid-order fix. v10 post-mortem: spill
// fixed (VGPR 28, WRITE 8 MB) and occupancy hit 59%, but FETCH exploded
// 12.8->69.7 MB because qt-fastest grid => XCD = qt%8 => every XCD touched
// all 32 bh (16 MB K/V working set >> 4 MB L2). v11 swaps to bh-fastest:
// XCD = bh%8 => each XCD serves exactly 4 bh (2 MB working set, L2-resident).
// Everything else identical to v10 (16 q-rows/wave, 32-key parity subtiles,
// 33 KB LDS, 4 blocks/CU, permlane P redistribution).
// ---------------------------------------------------------------------------
__global__ __launch_bounds__(512, 4) void flash_attn_mfma(
    const unsigned short* __restrict__ Q,   // [B,H,S,HD] bf16 (pre-scaled)
    const unsigned short* __restrict__ K,   // [B,H,S,HD] bf16
    const unsigned short* __restrict__ VT,  // [B,H,HD,S] bf16
    unsigned short* __restrict__ ctx) {     // [B,S,D] bf16
  const int bh = blockIdx.x;   // FASTEST: XCD = bh % 8 -> per-XCD K/V locality
  const int qt = blockIdx.y;   // 64-row q tile
  const int b  = bh >> 4;
  const int h  = bh & 15;
  const int t  = threadIdx.x;
  const int w  = t >> 6;   // wave 0..7
  const int l  = t & 63;
  const int wg = w & 3;    // q sub-tile 0..3 (16 rows each)
  const int wh = w >> 2;   // key-subtile parity 0/1
  const int g  = l >> 4;   // lane group 0..3
  const int ln = l & 15;   // q index within 16-row tile

  const unsigned short* Qp = Q + ((size_t)bh * SS + (size_t)qt * 64 + wg * 16) * HD;
  const unsigned short* Kp = K + (size_t)bh * SS * HD;
  const unsigned short* Vp = VT + (size_t)bh * HD * SS;

  // [K=0/V=1][parity][dbuf][4 KB tile]; K tile [32key][64hd], V tile [64hd][32key]
  __shared__ __align__(16) unsigned short smem[2][2][2][2048];
  __shared__ __align__(16) float rred[4 * 64];  // 1 KB combine scratch (rs)

  // Q as B-operand fragments: qf[kb], n=ln, k = kb*32 + g*8 + j
  bf16x8 qf[2];
#pragma unroll
  for (int kb = 0; kb < 2; ++kb)
    qf[kb] = *(const bf16x8*)(Qp + ln * HD + kb * 32 + g * 8);

  f32x4 o[4];
#pragma unroll
  for (int mt = 0; mt < 4; ++mt) o[mt] = (f32x4)0.f;
  float rs = 0.f;

  // stage one 64-key group (both parities): K 512 chunks + V 512 chunks,
  // 1 chunk of each per thread. Wave-uniform LDS dest (base + lane*16).
  const int sp  = w >> 2;          // parity this wave stages
  const int sq  = w & 3;           // quarter within parity tile
  auto stage = [&](int kt, int db) {
    {  // K: chunk idx within parity tile = sq*64 + l; row=idx>>3, cc=idx&7
      const int idx = sq * 64 + l;
      const int row = idx >> 3, cc = idx & 7;
      const int gcc = cc ^ (row & 7);
      async_copy16(Kp + (size_t)(kt * 64 + sp * 32 + row) * HD + gcc * 8,
                   &smem[0][sp][db][sq * 512]);
    }
    {  // V: row=idx>>2 (hd), c2=idx&3 (key chunk), swz ^((row>>1)&3)
      const int idx = sq * 64 + l;
      const int row = idx >> 2, c2 = idx & 3;
      const int gc2 = c2 ^ ((row >> 1) & 3);
      async_copy16(Vp + (size_t)row * SS + kt * 64 + sp * 32 + gc2 * 8,
                   &smem[1][sp][db][sq * 512]);
    }
  };

  stage(0, 0);
  for (int kt = 0; kt < SS / 64; ++kt) {   // 32 iterations
    const int db = kt & 1;
    __syncthreads();  // drains vmcnt -> buf[db] ready; buf[db^1] free
    if (kt + 1 < SS / 64) stage(kt + 1, db ^ 1);

    const unsigned short* Kst = &smem[0][wh][db][0];
    const unsigned short* Vst = &smem[1][wh][db][0];

    // --- S^T = K Q^T : st[mt][r] = S[key = mt*16+4g+r][q = ln]
    f32x4 st[2];
#pragma unroll
    for (int mt = 0; mt < 2; ++mt) st[mt] = (f32x4)0.f;
#pragma unroll
    for (int kb = 0; kb < 2; ++kb)
#pragma unroll
      for (int mt = 0; mt < 2; ++mt) {
        int row = mt * 16 + ln;
        bf16x8 ka = *(const bf16x8*)(&Kst[row * 64 + (((kb * 4 + g) ^ (row & 7)) * 8)]);
        st[mt] = __builtin_amdgcn_mfma_f32_16x16x32_bf16(ka, qf[kb], st[mt], 0, 0, 0);
      }

    // --- p = exp2(s'); pack bf16 pairs in-register; permlane redistribute
    unsigned Sd[2][2];  // [mt][p]: keys mt*16+4g+2p..+1, q=ln
#pragma unroll
    for (int mt = 0; mt < 2; ++mt) {
      float p0 = fast_exp2(st[mt][0]);
      float p1 = fast_exp2(st[mt][1]);
      float p2 = fast_exp2(st[mt][2]);
      float p3 = fast_exp2(st[mt][3]);
      Sd[mt][0] = __builtin_amdgcn_perm(__float_as_uint(p1), __float_as_uint(p0),
                                        0x07060302u);  // lo=p0,hi=p1
      Sd[mt][1] = __builtin_amdgcn_perm(__float_as_uint(p3), __float_as_uint(p2),
                                        0x07060302u);
      rs += (p0 + p1) + (p2 + p3);
    }
    // reg(mt) <-> lane-bit5, then reg <-> lane-bit4
#pragma unroll
    for (int p = 0; p < 2; ++p) pl32_swap(Sd[0][p], Sd[1][p]);
#pragma unroll
    for (int p = 0; p < 2; ++p) pl16_swap(Sd[0][p], Sd[1][p]);
    // Now Sd[i1][i0] = B-frag dword 2*i1+i0: keys g*8+2i..+1.

    // --- O^T += V^T P^T : P B-frag straight from registers (K-dim = 32)
    bf16x8 pbv;
    {
      union { unsigned u[4]; bf16x8 v; } cu;
      cu.u[0] = Sd[0][0];
      cu.u[1] = Sd[0][1];
      cu.u[2] = Sd[1][0];
      cu.u[3] = Sd[1][1];
      pbv = cu.v;
    }
#pragma unroll
    for (int mt = 0; mt < 4; ++mt) {
      int row = mt * 16 + ln;
      bf16x8 va = *(const bf16x8*)(&Vst[row * 32 + ((g ^ ((row >> 1) & 3)) * 8)]);
      o[mt] = __builtin_amdgcn_mfma_f32_16x16x32_bf16(va, pbv, o[mt], 0, 0, 0);
    }
  }

  // --- cross-parity combine: wh=1 waves dump partial o/rs to LDS, wh=0 adds.
  __syncthreads();  // all compute done; smem reusable as scratch
  {
    float* ored = (float*)&smem[0][0][0][0];  // 4 regions x 64 lanes x 16 f32 = 16 KB
    float* rb = ored + (wg * 64 + l) * 16;
    float* sb = rred + wg * 64 + l;
    if (wh == 1) {
#pragma unroll
      for (int mt = 0; mt < 4; ++mt)
        *(f32x4*)(rb + ((unsigned)(mt ^ (l & 3)) * 4)) = o[mt];
      sb[0] = rs;
    }
    __syncthreads();
    if (wh == 1) return;
#pragma unroll
    for (int mt = 0; mt < 4; ++mt) {
      f32x4 pv = *(const f32x4*)(rb + ((unsigned)(mt ^ (l & 3)) * 4));
      o[mt] += pv;
    }
    rs += sb[0];
  }

  // --- epilogue: reduce rs over lane groups, normalize, store bf16 ctx
  {
    float lsum = rs;
    lsum += __shfl_xor(lsum, 16, 64);
    lsum += __shfl_xor(lsum, 32, 64);
    float inv = 1.f / lsum;
    int srow = qt * 64 + wg * 16 + ln;
    unsigned short* cb = ctx + (size_t)(b * SS + srow) * DD + h * HD;
#pragma unroll
    for (int mt = 0; mt < 4; ++mt) {
      ushort4 u4;
      u4.x = f2bf(o[mt][0] * inv);
      u4.y = f2bf(o[mt][1] * inv);
      u4.z = f2bf(o[mt][2] * inv);
      u4.w = f2bf(o[mt][3] * inv);
      *(ushort4*)(cb + mt * 16 + 4 * g) = u4;
    }
  }
}

// ---------------------------------------------------------------------------
extern "C" void kernel_launch(void* const* d_in, const int* in_sizes, int n_in,
                              void* d_out, int out_size, void* d_ws, size_t ws_size,
                              hipStream_t stream) {
  const float* x  = (const float*)d_in[0];
  const float* Wq = (const float*)d_in[1];
  const float* bq = (const float*)d_in[2];
  const float* Wk = (const float*)d_in[3];
  const float* bk = (const float*)d_in[4];
  const float* Wv = (const float*)d_in[5];
  const float* bv = (const float*)d_in[6];
  const float* Wo = (const float*)d_in[7];
  const float* bo = (const float*)d_in[8];
  float* out = (float*)d_out;

  const size_t ELEMS = (size_t)BB * SS * DD;  // 4,194,304
  char* ws = (char*)d_ws;
  unsigned short* xb   = (unsigned short*)ws;  ws += ELEMS * 2;
  unsigned short* WqT  = (unsigned short*)ws;  ws += (size_t)DD * DD * 2;
  unsigned short* WkT  = (unsigned short*)ws;  ws += (size_t)DD * DD * 2;
  unsigned short* WvT  = (unsigned short*)ws;  ws += (size_t)DD * DD * 2;
  unsigned short* WoT  = (unsigned short*)ws;  ws += (size_t)DD * DD * 2;
  unsigned short* Qb   = (unsigned short*)ws;  ws += ELEMS * 2;
  unsigned short* Kb   = (unsigned short*)ws;  ws += ELEMS * 2;
  unsigned short* VbT  = (unsigned short*)ws;  ws += ELEMS * 2;
  unsigned short* ctxb = (unsigned short*)ws;  ws += ELEMS * 2;

  prep_kernel<<<8192, 256, 0, stream>>>(x, xb, Wq, WqT, Wk, WkT, Wv, WvT, Wo, WoT);

  qkv_gemm_8ph<<<192, 512, 0, stream>>>(xb, WqT, WkT, WvT, bq, bk, bv,
                                        Qb, Kb, VbT);

  dim3 attn_grid(BB * HH, SS / 64);            // (32 bh, 32 qt) = 1024 blocks
  flash_attn_mfma<<<attn_grid, 512, 0, stream>>>(Qb, Kb, VbT, ctxb);

  out_gemm_mfma<<<256, 256, 0, stream>>>(ctxb, WoT, bo, out);
}

// Round 8
// 196.607 us; speedup vs baseline: 1.5813x; 1.0086x over previous
//
#include <hip/hip_runtime.h>
#include <hip/hip_bf16.h>

#define BB 2
#define SS 2048
#define DD 1024
#define HH 16
#define HD 64

typedef __attribute__((ext_vector_type(8))) short bf16x8;
typedef __attribute__((ext_vector_type(4))) float f32x4;

// round-to-nearest-even f32 -> bf16 (inputs finite)
__device__ __forceinline__ unsigned short f2bf(float f) {
  unsigned int u = __float_as_uint(f);
  return (unsigned short)((u + 0x7FFFu + ((u >> 16) & 1u)) >> 16);
}

// 2^x via hardware v_exp_f32
__device__ __forceinline__ float fast_exp2(float x) {
#if __has_builtin(__builtin_amdgcn_exp2f)
  return __builtin_amdgcn_exp2f(x);
#else
  return __expf(x * 0.6931471805599453f);
#endif
}

__device__ __forceinline__ void async_copy16(const unsigned short* gp, unsigned short* lp) {
  __builtin_amdgcn_global_load_lds(
      (const __attribute__((address_space(1))) unsigned int*)gp,
      (__attribute__((address_space(3))) unsigned int*)lp, 16, 0, 0);
}

// gfx950 cross-lane register swaps (VALU, not DS pipe).
__device__ __forceinline__ void pl32_swap(unsigned& a, unsigned& b) {
#if __has_builtin(__builtin_amdgcn_permlane32_swap)
  auto r = __builtin_amdgcn_permlane32_swap(a, b, false, false);
  a = r[0];
  b = r[1];
#else
  asm volatile("v_permlane32_swap_b32 %0, %1" : "+v"(a), "+v"(b));
#endif
}
__device__ __forceinline__ void pl16_swap(unsigned& a, unsigned& b) {
#if __has_builtin(__builtin_amdgcn_permlane16_swap)
  auto r = __builtin_amdgcn_permlane16_swap(a, b, false, false);
  a = r[0];
  b = r[1];
#else
  asm volatile("v_permlane16_swap_b32 %0, %1" : "+v"(a), "+v"(b));
#endif
}

// ---------------------------------------------------------------------------
// Fused prep: blocks [0,4096) convert x -> bf16; blocks [4096,8192) transpose
// one of the 4 weight matrices (1024 32x32 tiles each) to bf16 [N][K].
// ---------------------------------------------------------------------------
__global__ __launch_bounds__(256) void prep_kernel(
    const float* __restrict__ x, unsigned short* __restrict__ xb,
    const float* __restrict__ W0, unsigned short* __restrict__ T0,
    const float* __restrict__ W1, unsigned short* __restrict__ T1,
    const float* __restrict__ W2, unsigned short* __restrict__ T2,
    const float* __restrict__ W3, unsigned short* __restrict__ T3) {
  const int blk = blockIdx.x;
  const int t = threadIdx.x;
  if (blk < 4096) {
    int i = blk * 1024 + t * 4;
    float4 v = *(const float4*)(x + i);
    ushort4 u;
    u.x = f2bf(v.x); u.y = f2bf(v.y); u.z = f2bf(v.z); u.w = f2bf(v.w);
    *(ushort4*)(xb + i) = u;
    return;
  }
  const int j = blk - 4096;
  const int jw = j >> 10;          // which weight
  const int tb = j & 1023;
  const float* W = jw == 0 ? W0 : (jw == 1 ? W1 : (jw == 2 ? W2 : W3));
  unsigned short* T = jw == 0 ? T0 : (jw == 1 ? T1 : (jw == 2 ? T2 : T3));
  __shared__ float tile[32][33];
  int k0 = (tb & 31) * 32, n0 = (tb >> 5) * 32;
  int c = t & 31, r0 = t >> 5;
#pragma unroll
  for (int i = 0; i < 4; ++i) {
    int r = r0 + i * 8;
    tile[r][c] = W[(size_t)(k0 + r) * DD + n0 + c];
  }
  __syncthreads();
#pragma unroll
  for (int i = 0; i < 4; ++i) {
    int r = r0 + i * 8;
    T[(size_t)(n0 + r) * DD + k0 + c] = f2bf(tile[c][r]);
  }
}

// ---------------------------------------------------------------------------
// bf16 MFMA GEMM core (m97 single-buffer, BK=32): D = A[M,K]@B^T[N,K] + bias
// STORE=0: fp32 out [M][DD]   (used by out-projection only)
// ---------------------------------------------------------------------------
template <int STORE>
__device__ __forceinline__ void gemm_core(
    const unsigned short* __restrict__ A, const unsigned short* __restrict__ BT,
    const float* __restrict__ bias, void* __restrict__ outp, float scale,
    int bm, int bn) {
  const int t = threadIdx.x;
  const int w = t >> 6;
  const int l = t & 63;
  const int wm = (w >> 1) * 64;
  const int wn = (w & 1) * 64;

  __shared__ __align__(16) unsigned short As[128 * 32];
  __shared__ __align__(16) unsigned short Bs[128 * 32];

  f32x4 acc[4][4];
#pragma unroll
  for (int i = 0; i < 4; ++i)
#pragma unroll
    for (int j = 0; j < 4; ++j) acc[i][j] = (f32x4)0.f;

  const int fr = l & 15;
  const int kg = (l >> 4) * 8;

  for (int k0 = 0; k0 < DD; k0 += 32) {
    __syncthreads();
#pragma unroll
    for (int c = 0; c < 2; ++c) {
      int e = (w * 2 + c) * 512 + l * 8;
      int row = e >> 5, kk = e & 31;
      async_copy16(A + (size_t)(bm + row) * DD + k0 + kk, As + (w * 2 + c) * 512);
      async_copy16(BT + (size_t)(bn + row) * DD + k0 + kk, Bs + (w * 2 + c) * 512);
    }
    __syncthreads();

    bf16x8 af[4], bfr[4];
#pragma unroll
    for (int i = 0; i < 4; ++i)
      af[i] = *(const bf16x8*)(As + (wm + i * 16 + fr) * 32 + kg);
#pragma unroll
    for (int j = 0; j < 4; ++j)
      bfr[j] = *(const bf16x8*)(Bs + (wn + j * 16 + fr) * 32 + kg);
#pragma unroll
    for (int i = 0; i < 4; ++i)
#pragma unroll
      for (int j = 0; j < 4; ++j)
        acc[i][j] = __builtin_amdgcn_mfma_f32_16x16x32_bf16(af[i], bfr[j], acc[i][j], 0, 0, 0);
  }

  const int col_l = l & 15;
  const int row_l = (l >> 4) * 4;

#pragma unroll
  for (int i = 0; i < 4; ++i) {
    int m_base = bm + wm + i * 16 + row_l;
#pragma unroll
    for (int j = 0; j < 4; ++j) {
      int n = bn + wn + j * 16 + col_l;
      float bv = bias[n];
      float* out = (float*)outp;
#pragma unroll
      for (int r = 0; r < 4; ++r)
        out[(size_t)(m_base + r) * DD + n] = acc[i][j][r] + bv;
    }
  }
}

// output projection, 256 blocks, XCD-swizzled (8 bn per bm on one XCD)
__global__ __launch_bounds__(256) void out_gemm_mfma(
    const unsigned short* __restrict__ A, const unsigned short* __restrict__ WoT,
    const float* __restrict__ bo, float* __restrict__ out) {
  const int i = blockIdx.x;
  const int xcd = i & 7;
  const int slot = i >> 3;            // 0..31
  const int bm = (xcd + 8 * (slot >> 3)) * 128;
  const int bn = (slot & 7) * 128;
  gemm_core<0>(A, WoT, bo, (void*)out, 1.0f, bm, bn);
}

// ---------------------------------------------------------------------------
// QKV projection, 8-phase 256x256xBK64 template (T2+T3+T4+T5). Verified R3.
// ---------------------------------------------------------------------------
#define QPHASE(DB, KH, MH, S, VM) do {                                        \
    bf16x8 af[4];                                                             \
    _Pragma("unroll")                                                         \
    for (int ii = 0; ii < 4; ++ii) {                                          \
      int row = wm * 128 + (MH) * 64 + ii * 16 + fr;                          \
      int kb = kg16 ^ ((row & 8) ? 32 : 0) ^ ((row & 4) ? 16 : 0);            \
      af[ii] = *(const bf16x8*)((const char*)&lds[0][DB][KH][0] + row * 64 + kb); \
    }                                                                         \
    if ((MH) == 0) {                                                          \
      _Pragma("unroll")                                                       \
      for (int j = 0; j < 4; ++j) {                                           \
        int row = wn * 64 + j * 16 + fr;                                      \
        int kb = kg16 ^ ((row & 8) ? 32 : 0) ^ ((row & 4) ? 16 : 0);          \
        bfr[j] = *(const bf16x8*)((const char*)&lds[1][DB][KH][0] + row * 64 + kb); \
      }                                                                       \
    }                                                                         \
    stage_half(S);                                                            \
    asm volatile("s_barrier" ::: "memory");                                   \
    __builtin_amdgcn_s_setprio(1);                                            \
    _Pragma("unroll")                                                         \
    for (int ii = 0; ii < 4; ++ii)                                            \
      _Pragma("unroll")                                                       \
      for (int j = 0; j < 4; ++j)                                             \
        acc[(MH) * 4 + ii][j] = __builtin_amdgcn_mfma_f32_16x16x32_bf16(      \
            af[ii], bfr[j], acc[(MH) * 4 + ii][j], 0, 0, 0);                  \
    __builtin_amdgcn_s_setprio(0);                                            \
    if ((VM) == 1) asm volatile("s_waitcnt vmcnt(4)" ::: "memory");           \
    if ((VM) == 2) asm volatile("s_waitcnt vmcnt(0)" ::: "memory");           \
    asm volatile("s_barrier" ::: "memory");                                   \
  } while (0)

__global__ __launch_bounds__(512, 2) void qkv_gemm_8ph(
    const unsigned short* __restrict__ A,
    const unsigned short* __restrict__ WqT, const unsigned short* __restrict__ WkT,
    const unsigned short* __restrict__ WvT,
    const float* __restrict__ bq, const float* __restrict__ bk,
    const float* __restrict__ bv,
    unsigned short* __restrict__ Qo, unsigned short* __restrict__ Ko,
    unsigned short* __restrict__ VTo) {
  const int i = blockIdx.x;
  const int xcd = i & 7;
  const int slot = i >> 3;              // 0..23
  const int bmi = xcd * 2 + (slot / 12);
  const int c = slot % 12;
  const int which = c >> 2;             // 0:Q 1:K 2:V
  const int bm = bmi * 256;
  const int bn = (c & 3) * 256;
  const unsigned short* BT = which == 0 ? WqT : (which == 1 ? WkT : WvT);
  const float* bias = which == 0 ? bq : (which == 1 ? bk : bv);

  const int t = threadIdx.x;
  const int w = t >> 6;
  const int l = t & 63;
  const int wm = w >> 2;        // 0..1 (M)
  const int wn = w & 3;         // 0..3 (N)
  const int fr = l & 15;
  const int kg16 = (l >> 4) * 16;   // byte offset of lane's k-group in 32k half

  // [mat A/B][dbuf][khalf][256 rows x 32 k] bf16, 128 KiB total
  __shared__ __align__(16) unsigned short lds[2][2][2][8192];

  f32x4 acc[8][4];
#pragma unroll
  for (int mi = 0; mi < 8; ++mi)
#pragma unroll
    for (int j = 0; j < 4; ++j) acc[mi][j] = (f32x4)0.f;

  // stage half-tile s (s = 4*T + {0:A_k0,1:B_k0,2:A_k1,3:B_k1}); 2 loads/thr
  auto stage_half = [&](int s) {
    if (s >= 64) return;
    const int Ts = s >> 2;
    const int db = Ts & 1;
    const int typ = s & 3;
    const int kh = typ >> 1;
    const int isB = typ & 1;
    const unsigned short* src = isB ? BT : A;
    const int rbase = isB ? bn : bm;
    unsigned short* dstbase = &lds[isB][db][kh][0];
    const int k0 = Ts * 64 + kh * 32;
#pragma unroll
    for (int j = 0; j < 2; ++j) {
      int cc = (w * 2 + j) * 64 + l;    // 16B chunk 0..1023
      int row = cc >> 2;
      int ke = ((cc & 3) * 8) ^ ((row & 8) ? 16 : 0) ^ ((row & 4) ? 8 : 0);
      async_copy16(src + (size_t)(rbase + row) * DD + k0 + ke,
                   dstbase + (w * 2 + j) * 512);
    }
  };

  bf16x8 bfr[4];

  // prologue: tile0 (4 halves) + tile1 first 2 halves; wait tile0 landed
  for (int s = 0; s < 6; ++s) stage_half(s);
  asm volatile("s_waitcnt vmcnt(4)" ::: "memory");
  asm volatile("s_barrier" ::: "memory");

  for (int T = 0; T < 14; ++T) {
    const int db = T & 1;
    const int sb = 4 * T + 6;
    QPHASE(db, 0, 0, sb + 0, 0);
    QPHASE(db, 0, 1, sb + 1, 0);
    QPHASE(db, 1, 0, sb + 2, 0);
    QPHASE(db, 1, 1, sb + 3, 1);      // boundary: vmcnt(4)
  }
  // T = 14 (db 0): stages s=62,63 then exhausted; final drain at boundary
  QPHASE(0, 0, 0, 62, 0);
  QPHASE(0, 0, 1, 63, 0);
  QPHASE(0, 1, 0, 64, 0);
  QPHASE(0, 1, 1, 64, 2);             // vmcnt(0): everything landed
  // T = 15 (db 1): no staging, no waits needed
  QPHASE(1, 0, 0, 64, 0);
  QPHASE(1, 0, 1, 64, 0);
  QPHASE(1, 1, 0, 64, 0);
  QPHASE(1, 1, 1, 64, 0);

  const int col_l = l & 15;
  const int row_l = (l >> 4) * 4;
  const int b_ = bm >> 11;

  if (which != 2) {
    // Q/K: bf16 out [B,H,S,HD], scaled
    const float scl = which == 0 ? 0.18033688011112042f : 1.0f;
    unsigned short* out = which == 0 ? Qo : Ko;
#pragma unroll
    for (int mi = 0; mi < 8; ++mi) {
      int m_base = bm + wm * 128 + mi * 16 + row_l;
#pragma unroll
      for (int j = 0; j < 4; ++j) {
        int n = bn + wn * 64 + j * 16 + col_l;
        float bv = bias[n];
        int h_ = n >> 6, hd_ = n & 63;
#pragma unroll
        for (int r = 0; r < 4; ++r) {
          int m = m_base + r;
          int b2 = m >> 11, s_ = m & 2047;
          out[(((size_t)(b2 * HH + h_) * SS) + s_) * HD + hd_] =
              f2bf((acc[mi][j][r] + bv) * scl);
        }
      }
    }
  } else {
    // V: transpose 256x256 C tile via LDS -> VTo[(b*HH+h)*HD+hd][s]
    unsigned int* Tt = (unsigned int*)&lds[0][0][0][0];  // 32768 dwords
#pragma unroll
    for (int mi = 0; mi < 8; ++mi) {
      int m2a = wm * 64 + mi * 8 + (l >> 4) * 2;  // dword index (m pair), even
#pragma unroll
      for (int j = 0; j < 4; ++j) {
        int n = wn * 64 + j * 16 + col_l;
        float bv = bias[bn + n];
        uint2 dd;
        dd.x = (unsigned)f2bf(acc[mi][j][0] + bv) |
               ((unsigned)f2bf(acc[mi][j][1] + bv) << 16);
        dd.y = (unsigned)f2bf(acc[mi][j][2] + bv) |
               ((unsigned)f2bf(acc[mi][j][3] + bv) << 16);
        *(uint2*)(Tt + n * 128 + (m2a ^ ((n & 7) << 2))) = dd;
      }
    }
    __syncthreads();
    const int srow0 = bm & 2047;
    const int n_r = t >> 1;
    const int half = t & 1;
    const int n_glob = bn + n_r;
    const int h_ = n_glob >> 6, hd_ = n_glob & 63;
    unsigned short* ob =
        VTo + ((size_t)((b_ * HH + h_) * HD + hd_)) * SS + srow0 + half * 128;
#pragma unroll
    for (int cp = 0; cp < 16; ++cp) {
      uint4 v = *(const uint4*)(Tt + n_r * 128 +
                                ((half * 64 + cp * 4) ^ ((n_r & 7) << 2)));
      *(uint4*)(ob + cp * 8) = v;
    }
  }
}

// ---------------------------------------------------------------------------
// MFMA flash attention v12 = v11 + loop-invariant address hoisting.
// v11 post-mortem: FETCH fixed (12.3 MB) but dur 50.7us; VALUBusy 49% =
// ~59K cyc/SIMD vs ~25K of algorithmic VALU (exp2/pack/permlane/adds) ->
// the other ~half is per-iteration ADDRESS RECOMPUTATION (8 swizzled LDS
// read addrs + 2 64-bit global staging addrs rebuilt each iter; db-toggling
// bases defeat LICM). v12: (a) precompute ds_read byte offsets ko[kb][mt]/
// vo[mt] once (lane constants); (b) staging via 2 pointers advanced by
// constant strides; (c) manual unroll-by-2 so db is a literal -> LDS bases
// fold. No algorithmic change. VGPR 28 -> ~44 (cap 64, no spill).
// ---------------------------------------------------------------------------
__global__ __launch_bounds__(512, 4) void flash_attn_mfma(
    const unsigned short* __restrict__ Q,   // [B,H,S,HD] bf16 (pre-scaled)
    const unsigned short* __restrict__ K,   // [B,H,S,HD] bf16
    const unsigned short* __restrict__ VT,  // [B,H,HD,S] bf16
    unsigned short* __restrict__ ctx) {     // [B,S,D] bf16
  const int bh = blockIdx.x;   // FASTEST: XCD = bh % 8 -> per-XCD K/V locality
  const int qt = blockIdx.y;   // 64-row q tile
  const int b  = bh >> 4;
  const int h  = bh & 15;
  const int t  = threadIdx.x;
  const int w  = t >> 6;   // wave 0..7
  const int l  = t & 63;
  const int wg = w & 3;    // q sub-tile 0..3 (16 rows each)
  const int wh = w >> 2;   // key-subtile parity 0/1
  const int g  = l >> 4;   // lane group 0..3
  const int ln = l & 15;   // q index within 16-row tile

  const unsigned short* Qp = Q + ((size_t)bh * SS + (size_t)qt * 64 + wg * 16) * HD;
  const unsigned short* Kp = K + (size_t)bh * SS * HD;
  const unsigned short* Vp = VT + (size_t)bh * HD * SS;

  // [K=0/V=1][parity][dbuf][4 KB tile]; K tile [32key][64hd], V tile [64hd][32key]
  __shared__ __align__(16) unsigned short smem[2][2][2][2048];
  __shared__ __align__(16) float rred[4 * 64];  // 1 KB combine scratch (rs)

  // Q as B-operand fragments: qf[kb], n=ln, k = kb*32 + g*8 + j
  bf16x8 qf[2];
#pragma unroll
  for (int kb = 0; kb < 2; ++kb)
    qf[kb] = *(const bf16x8*)(Qp + ln * HD + kb * 32 + g * 8);

  f32x4 o[4];
#pragma unroll
  for (int mt = 0; mt < 4; ++mt) o[mt] = (f32x4)0.f;
  float rs = 0.f;

  // ---- loop-invariant staging pointers (advance by const stride per tile)
  const int sp  = w >> 2;          // parity this wave stages
  const int sq  = w & 3;           // quarter within parity tile
  const int idx = sq * 64 + l;
  const int rowK = idx >> 3;
  const int gccK = (idx & 7) ^ (rowK & 7);
  const unsigned short* kgp = Kp + (size_t)(sp * 32 + rowK) * HD + gccK * 8;
  const int rowV = idx >> 2;
  const int gc2V = (idx & 3) ^ ((rowV >> 1) & 3);
  const unsigned short* vgp = Vp + (size_t)rowV * SS + sp * 32 + gc2V * 8;
  unsigned short* dK = &smem[0][sp][0][sq * 512];   // +2048 shorts for db=1
  unsigned short* dV = &smem[1][sp][0][sq * 512];

  // ---- loop-invariant ds_read byte offsets (pure lane constants)
  int ko[2][2];
#pragma unroll
  for (int kb = 0; kb < 2; ++kb)
#pragma unroll
    for (int mt = 0; mt < 2; ++mt) {
      int row = mt * 16 + ln;
      ko[kb][mt] = row * 128 + (((kb * 4 + g) ^ (row & 7)) * 16);
    }
  int vo[4];
#pragma unroll
  for (int mt = 0; mt < 4; ++mt) {
    int row = mt * 16 + ln;
    vo[mt] = row * 64 + ((g ^ ((row >> 1) & 3)) * 16);
  }
  const char* kpar = (const char*)&smem[0][wh][0][0];
  const char* vpar = (const char*)&smem[1][wh][0][0];

  auto stage_i = [&](int db) {
    async_copy16(kgp, dK + db * 2048);
    async_copy16(vgp, dV + db * 2048);
    kgp += 64 * HD;   // next 64-key group along s
    vgp += 64;
  };

  auto body = [&](int db) {
    const char* Kst = kpar + db * 4096;
    const char* Vst = vpar + db * 4096;

    // --- S^T = K Q^T : st[mt][r] = S[key = mt*16+4g+r][q = ln]
    f32x4 st[2];
#pragma unroll
    for (int mt = 0; mt < 2; ++mt) st[mt] = (f32x4)0.f;
#pragma unroll
    for (int kb = 0; kb < 2; ++kb)
#pragma unroll
      for (int mt = 0; mt < 2; ++mt) {
        bf16x8 ka = *(const bf16x8*)(Kst + ko[kb][mt]);
        st[mt] = __builtin_amdgcn_mfma_f32_16x16x32_bf16(ka, qf[kb], st[mt], 0, 0, 0);
      }

    // --- p = exp2(s'); pack bf16 pairs in-register; permlane redistribute
    unsigned Sd[2][2];  // [mt][p]: keys mt*16+4g+2p..+1, q=ln
#pragma unroll
    for (int mt = 0; mt < 2; ++mt) {
      float p0 = fast_exp2(st[mt][0]);
      float p1 = fast_exp2(st[mt][1]);
      float p2 = fast_exp2(st[mt][2]);
      float p3 = fast_exp2(st[mt][3]);
      Sd[mt][0] = __builtin_amdgcn_perm(__float_as_uint(p1), __float_as_uint(p0),
                                        0x07060302u);  // lo=p0,hi=p1
      Sd[mt][1] = __builtin_amdgcn_perm(__float_as_uint(p3), __float_as_uint(p2),
                                        0x07060302u);
      rs += (p0 + p1) + (p2 + p3);
    }
    // reg(mt) <-> lane-bit5, then reg <-> lane-bit4
#pragma unroll
    for (int p = 0; p < 2; ++p) pl32_swap(Sd[0][p], Sd[1][p]);
#pragma unroll
    for (int p = 0; p < 2; ++p) pl16_swap(Sd[0][p], Sd[1][p]);
    // Now Sd[i1][i0] = B-frag dword 2*i1+i0: keys g*8+2i..+1.

    // --- O^T += V^T P^T : P B-frag straight from registers (K-dim = 32)
    bf16x8 pbv;
    {
      union { unsigned u[4]; bf16x8 v; } cu;
      cu.u[0] = Sd[0][0];
      cu.u[1] = Sd[0][1];
      cu.u[2] = Sd[1][0];
      cu.u[3] = Sd[1][1];
      pbv = cu.v;
    }
#pragma unroll
    for (int mt = 0; mt < 4; ++mt) {
      bf16x8 va = *(const bf16x8*)(Vst + vo[mt]);
      o[mt] = __builtin_amdgcn_mfma_f32_16x16x32_bf16(va, pbv, o[mt], 0, 0, 0);
    }
  };

  // prologue: tile 0 -> db0
  stage_i(0);
  for (int kt2 = 0; kt2 < 16; ++kt2) {   // 2 key-tiles per iteration
    __syncthreads();                     // db0 ready; db1 free
    stage_i(1);                          // tile 2*kt2+1 -> db1
    body(0);                             // compute tile 2*kt2
    __syncthreads();                     // db1 ready; db0 free
    if (kt2 < 15) stage_i(0);            // tile 2*kt2+2 -> db0
    body(1);                             // compute tile 2*kt2+1
  }

  // --- cross-parity combine: wh=1 waves dump partial o/rs to LDS, wh=0 adds.
  __syncthreads();  // all compute done; smem reusable as scratch
  {
    float* ored = (float*)&smem[0][0][0][0];  // 4 regions x 64 lanes x 16 f32 = 16 KB
    float* rb = ored + (wg * 64 + l) * 16;
    float* sb = rred + wg * 64 + l;
    if (wh == 1) {
#pragma unroll
      for (int mt = 0; mt < 4; ++mt)
        *(f32x4*)(rb + ((unsigned)(mt ^ (l & 3)) * 4)) = o[mt];
      sb[0] = rs;
    }
    __syncthreads();
    if (wh == 1) return;
#pragma unroll
    for (int mt = 0; mt < 4; ++mt) {
      f32x4 pv = *(const f32x4*)(rb + ((unsigned)(mt ^ (l & 3)) * 4));
      o[mt] += pv;
    }
    rs += sb[0];
  }

  // --- epilogue: reduce rs over lane groups, normalize, store bf16 ctx
  {
    float lsum = rs;
    lsum += __shfl_xor(lsum, 16, 64);
    lsum += __shfl_xor(lsum, 32, 64);
    float inv = 1.f / lsum;
    int srow = qt * 64 + wg * 16 + ln;
    unsigned short* cb = ctx + (size_t)(b * SS + srow) * DD + h * HD;
#pragma unroll
    for (int mt = 0; mt < 4; ++mt) {
      ushort4 u4;
      u4.x = f2bf(o[mt][0] * inv);
      u4.y = f2bf(o[mt][1] * inv);
      u4.z = f2bf(o[mt][2] * inv);
      u4.w = f2bf(o[mt][3] * inv);
      *(ushort4*)(cb + mt * 16 + 4 * g) = u4;
    }
  }
}

// ---------------------------------------------------------------------------
extern "C" void kernel_launch(void* const* d_in, const int* in_sizes, int n_in,
                              void* d_out, int out_size, void* d_ws, size_t ws_size,
                              hipStream_t stream) {
  const float* x  = (const float*)d_in[0];
  const float* Wq = (const float*)d_in[1];
  const float* bq = (const float*)d_in[2];
  const float* Wk = (const float*)d_in[3];
  const float* bk = (const float*)d_in[4];
  const float* Wv = (const float*)d_in[5];
  const float* bv = (const float*)d_in[6];
  const float* Wo = (const float*)d_in[7];
  const float* bo = (const float*)d_in[8];
  float* out = (float*)d_out;

  const size_t ELEMS = (size_t)BB * SS * DD;  // 4,194,304
  char* ws = (char*)d_ws;
  unsigned short* xb   = (unsigned short*)ws;  ws += ELEMS * 2;
  unsigned short* WqT  = (unsigned short*)ws;  ws += (size_t)DD * DD * 2;
  unsigned short* WkT  = (unsigned short*)ws;  ws += (size_t)DD * DD * 2;
  unsigned short* WvT  = (unsigned short*)ws;  ws += (size_t)DD * DD * 2;
  unsigned short* WoT  = (unsigned short*)ws;  ws += (size_t)DD * DD * 2;
  unsigned short* Qb   = (unsigned short*)ws;  ws += ELEMS * 2;
  unsigned short* Kb   = (unsigned short*)ws;  ws += ELEMS * 2;
  unsigned short* VbT  = (unsigned short*)ws;  ws += ELEMS * 2;
  unsigned short* ctxb = (unsigned short*)ws;  ws += ELEMS * 2;

  prep_kernel<<<8192, 256, 0, stream>>>(x, xb, Wq, WqT, Wk, WkT, Wv, WvT, Wo, WoT);

  qkv_gemm_8ph<<<192, 512, 0, stream>>>(xb, WqT, WkT, WvT, bq, bk, bv,
                                        Qb, Kb, VbT);

  dim3 attn_grid(BB * HH, SS / 64);            // (32 bh, 32 qt) = 1024 blocks
  flash_attn_mfma<<<attn_grid, 512, 0, stream>>>(Qb, Kb, VbT, ctxb);

  out_gemm_mfma<<<256, 256, 0, stream>>>(ctxb, WoT, bo, out);
}

// Round 9
// 193.725 us; speedup vs baseline: 1.6048x; 1.0149x over previous
//
#include <hip/hip_runtime.h>
#include <hip/hip_bf16.h>

#define BB 2
#define SS 2048
#define DD 1024
#define HH 16
#define HD 64

typedef __attribute__((ext_vector_type(8))) short bf16x8;
typedef __attribute__((ext_vector_type(4))) float f32x4;

// round-to-nearest-even f32 -> bf16 (inputs finite)
__device__ __forceinline__ unsigned short f2bf(float f) {
  unsigned int u = __float_as_uint(f);
  return (unsigned short)((u + 0x7FFFu + ((u >> 16) & 1u)) >> 16);
}

// 2^x via hardware v_exp_f32
__device__ __forceinline__ float fast_exp2(float x) {
#if __has_builtin(__builtin_amdgcn_exp2f)
  return __builtin_amdgcn_exp2f(x);
#else
  return __expf(x * 0.6931471805599453f);
#endif
}

__device__ __forceinline__ void async_copy16(const unsigned short* gp, unsigned short* lp) {
  __builtin_amdgcn_global_load_lds(
      (const __attribute__((address_space(1))) unsigned int*)gp,
      (__attribute__((address_space(3))) unsigned int*)lp, 16, 0, 0);
}

// gfx950 cross-lane register swaps (VALU, not DS pipe).
__device__ __forceinline__ void pl32_swap(unsigned& a, unsigned& b) {
#if __has_builtin(__builtin_amdgcn_permlane32_swap)
  auto r = __builtin_amdgcn_permlane32_swap(a, b, false, false);
  a = r[0];
  b = r[1];
#else
  asm volatile("v_permlane32_swap_b32 %0, %1" : "+v"(a), "+v"(b));
#endif
}
__device__ __forceinline__ void pl16_swap(unsigned& a, unsigned& b) {
#if __has_builtin(__builtin_amdgcn_permlane16_swap)
  auto r = __builtin_amdgcn_permlane16_swap(a, b, false, false);
  a = r[0];
  b = r[1];
#else
  asm volatile("v_permlane16_swap_b32 %0, %1" : "+v"(a), "+v"(b));
#endif
}

// ---------------------------------------------------------------------------
// Fused prep: blocks [0,4096) convert x -> bf16; blocks [4096,8192) transpose
// one of the 4 weight matrices (1024 32x32 tiles each) to bf16 [N][K].
// ---------------------------------------------------------------------------
__global__ __launch_bounds__(256) void prep_kernel(
    const float* __restrict__ x, unsigned short* __restrict__ xb,
    const float* __restrict__ W0, unsigned short* __restrict__ T0,
    const float* __restrict__ W1, unsigned short* __restrict__ T1,
    const float* __restrict__ W2, unsigned short* __restrict__ T2,
    const float* __restrict__ W3, unsigned short* __restrict__ T3) {
  const int blk = blockIdx.x;
  const int t = threadIdx.x;
  if (blk < 4096) {
    int i = blk * 1024 + t * 4;
    float4 v = *(const float4*)(x + i);
    ushort4 u;
    u.x = f2bf(v.x); u.y = f2bf(v.y); u.z = f2bf(v.z); u.w = f2bf(v.w);
    *(ushort4*)(xb + i) = u;
    return;
  }
  const int j = blk - 4096;
  const int jw = j >> 10;          // which weight
  const int tb = j & 1023;
  const float* W = jw == 0 ? W0 : (jw == 1 ? W1 : (jw == 2 ? W2 : W3));
  unsigned short* T = jw == 0 ? T0 : (jw == 1 ? T1 : (jw == 2 ? T2 : T3));
  __shared__ float tile[32][33];
  int k0 = (tb & 31) * 32, n0 = (tb >> 5) * 32;
  int c = t & 31, r0 = t >> 5;
#pragma unroll
  for (int i = 0; i < 4; ++i) {
    int r = r0 + i * 8;
    tile[r][c] = W[(size_t)(k0 + r) * DD + n0 + c];
  }
  __syncthreads();
#pragma unroll
  for (int i = 0; i < 4; ++i) {
    int r = r0 + i * 8;
    T[(size_t)(n0 + r) * DD + k0 + c] = f2bf(tile[c][r]);
  }
}

// ---------------------------------------------------------------------------
// bf16 MFMA GEMM core (m97 single-buffer, BK=32): D = A[M,K]@B^T[N,K] + bias
// STORE=0: fp32 out [M][DD]   (used by out-projection only)
// ---------------------------------------------------------------------------
template <int STORE>
__device__ __forceinline__ void gemm_core(
    const unsigned short* __restrict__ A, const unsigned short* __restrict__ BT,
    const float* __restrict__ bias, void* __restrict__ outp, float scale,
    int bm, int bn) {
  const int t = threadIdx.x;
  const int w = t >> 6;
  const int l = t & 63;
  const int wm = (w >> 1) * 64;
  const int wn = (w & 1) * 64;

  __shared__ __align__(16) unsigned short As[128 * 32];
  __shared__ __align__(16) unsigned short Bs[128 * 32];

  f32x4 acc[4][4];
#pragma unroll
  for (int i = 0; i < 4; ++i)
#pragma unroll
    for (int j = 0; j < 4; ++j) acc[i][j] = (f32x4)0.f;

  const int fr = l & 15;
  const int kg = (l >> 4) * 8;

  for (int k0 = 0; k0 < DD; k0 += 32) {
    __syncthreads();
#pragma unroll
    for (int c = 0; c < 2; ++c) {
      int e = (w * 2 + c) * 512 + l * 8;
      int row = e >> 5, kk = e & 31;
      async_copy16(A + (size_t)(bm + row) * DD + k0 + kk, As + (w * 2 + c) * 512);
      async_copy16(BT + (size_t)(bn + row) * DD + k0 + kk, Bs + (w * 2 + c) * 512);
    }
    __syncthreads();

    bf16x8 af[4], bfr[4];
#pragma unroll
    for (int i = 0; i < 4; ++i)
      af[i] = *(const bf16x8*)(As + (wm + i * 16 + fr) * 32 + kg);
#pragma unroll
    for (int j = 0; j < 4; ++j)
      bfr[j] = *(const bf16x8*)(Bs + (wn + j * 16 + fr) * 32 + kg);
#pragma unroll
    for (int i = 0; i < 4; ++i)
#pragma unroll
      for (int j = 0; j < 4; ++j)
        acc[i][j] = __builtin_amdgcn_mfma_f32_16x16x32_bf16(af[i], bfr[j], acc[i][j], 0, 0, 0);
  }

  const int col_l = l & 15;
  const int row_l = (l >> 4) * 4;

#pragma unroll
  for (int i = 0; i < 4; ++i) {
    int m_base = bm + wm + i * 16 + row_l;
#pragma unroll
    for (int j = 0; j < 4; ++j) {
      int n = bn + wn + j * 16 + col_l;
      float bv = bias[n];
      float* out = (float*)outp;
#pragma unroll
      for (int r = 0; r < 4; ++r)
        out[(size_t)(m_base + r) * DD + n] = acc[i][j][r] + bv;
    }
  }
}

// output projection, 256 blocks, XCD-swizzled (8 bn per bm on one XCD)
__global__ __launch_bounds__(256) void out_gemm_mfma(
    const unsigned short* __restrict__ A, const unsigned short* __restrict__ WoT,
    const float* __restrict__ bo, float* __restrict__ out) {
  const int i = blockIdx.x;
  const int xcd = i & 7;
  const int slot = i >> 3;            // 0..31
  const int bm = (xcd + 8 * (slot >> 3)) * 128;
  const int bn = (slot & 7) * 128;
  gemm_core<0>(A, WoT, bo, (void*)out, 1.0f, bm, bn);
}

// ---------------------------------------------------------------------------
// QKV projection v2: 128x128xBK32 tiles, 768 blocks (3/CU coverage), 4 waves,
// TRIPLE-buffered LDS (3 x 16 KB = 48 KB) with the R3-proven raw-asm
// counted-vmcnt schedule. R8 post-mortem of the 256^2 8-phase kernel:
// grid 192 < 256 CUs (25% idle), 1 block/CU, MfmaUtil 16%, Occ 13%.
// Here: stage tile T+2 during phase T (4 global_load_lds/thread), wait
// vmcnt(4) at each phase end (tile T+1 landed, T+2 in flight) -- never
// drain-0 in the loop. setprio around the 16-MFMA cluster. Read offsets
// hoisted (lane constants). Epilogues verbatim from the R2 harness-passed
// 128^2 kernel (Q/K scatter bf16; V LDS-transpose). K-accumulation order
// identical to R2 (bit-identical numerics path).
// Race safety: stage(T+2) writes buf (T+2)%3 = (T-1)%3, whose last reads
// completed before the end-of-phase-(T-1) barrier (lgkmcnt consumed by
// that phase's MFMAs). vmcnt(4) at end of T guarantees tile T+1 landed.
// ---------------------------------------------------------------------------
__global__ __launch_bounds__(256, 3) void qkv_gemm_tri(
    const unsigned short* __restrict__ A,
    const unsigned short* __restrict__ WqT, const unsigned short* __restrict__ WkT,
    const unsigned short* __restrict__ WvT,
    const float* __restrict__ bq, const float* __restrict__ bk,
    const float* __restrict__ bv,
    unsigned short* __restrict__ Qo, unsigned short* __restrict__ Ko,
    unsigned short* __restrict__ VTo) {
  const int i = blockIdx.x;
  const int xcd = i & 7;
  const int slot = i >> 3;              // 0..95
  const int bm = (xcd + 8 * (slot / 24)) * 128;   // 24 blocks share A-panel/XCD
  const int c = slot % 24;
  const int which = c >> 3;             // 0:Q 1:K 2:V
  const int bn = (c & 7) * 128;
  const unsigned short* BT = which == 0 ? WqT : (which == 1 ? WkT : WvT);
  const float* bias = which == 0 ? bq : (which == 1 ? bk : bv);

  const int t = threadIdx.x;
  const int w = t >> 6;
  const int l = t & 63;
  const int wm = (w >> 1) * 64;
  const int wn = (w & 1) * 64;
  const int fr = l & 15;
  const int kgB = (l >> 4) * 16;        // byte offset of lane's k-group

  // [A=0/B=1][tri][128 rows x 32 k] bf16 = 48 KB -> 3 blocks/CU
  __shared__ __align__(16) unsigned short lds[2][3][4096];

  f32x4 acc[4][4];
#pragma unroll
  for (int ii = 0; ii < 4; ++ii)
#pragma unroll
    for (int j = 0; j < 4; ++j) acc[ii][j] = (f32x4)0.f;

  // hoisted LDS read byte offsets (lane constants)
  int aoff[4], boff[4];
#pragma unroll
  for (int ii = 0; ii < 4; ++ii) {
    aoff[ii] = (wm + ii * 16 + fr) * 64 + kgB;
    boff[ii] = (wn + ii * 16 + fr) * 64 + kgB;
  }

  // hoisted staging source pointers (advance by literal k0 per tile)
  const int cc0 = w * 128 + l;          // (w*2+0)*64 + l
  const int cc1 = cc0 + 64;
  const int row0 = cc0 >> 2, kk0 = (cc0 & 3) * 8;
  const int row1 = cc1 >> 2, kk1 = (cc1 & 3) * 8;
  const unsigned short* a0 = A + (size_t)(bm + row0) * DD + kk0;
  const unsigned short* a1 = A + (size_t)(bm + row1) * DD + kk1;
  const unsigned short* b0 = BT + (size_t)(bn + row0) * DD + kk0;
  const unsigned short* b1 = BT + (size_t)(bn + row1) * DD + kk1;

  auto stage_tile = [&](int T) {
    if (T >= 32) return;
    const int buf = T % 3;
    const int k0 = T * 32;
    async_copy16(a0 + k0, &lds[0][buf][w * 1024]);
    async_copy16(a1 + k0, &lds[0][buf][w * 1024 + 512]);
    async_copy16(b0 + k0, &lds[1][buf][w * 1024]);
    async_copy16(b1 + k0, &lds[1][buf][w * 1024 + 512]);
  };

  auto phase = [&](int T, int vm) {
    const int buf = T % 3;
    const char* Ab = (const char*)&lds[0][buf][0];
    const char* Bb = (const char*)&lds[1][buf][0];
    bf16x8 af[4], bfr[4];
#pragma unroll
    for (int ii = 0; ii < 4; ++ii) af[ii] = *(const bf16x8*)(Ab + aoff[ii]);
#pragma unroll
    for (int j = 0; j < 4; ++j) bfr[j] = *(const bf16x8*)(Bb + boff[j]);
    stage_tile(T + 2);
    asm volatile("s_barrier" ::: "memory");
    __builtin_amdgcn_s_setprio(1);
#pragma unroll
    for (int ii = 0; ii < 4; ++ii)
#pragma unroll
      for (int j = 0; j < 4; ++j)
        acc[ii][j] = __builtin_amdgcn_mfma_f32_16x16x32_bf16(af[ii], bfr[j], acc[ii][j], 0, 0, 0);
    __builtin_amdgcn_s_setprio(0);
    if (vm == 1) asm volatile("s_waitcnt vmcnt(4)" ::: "memory");
    if (vm == 2) asm volatile("s_waitcnt vmcnt(0)" ::: "memory");
    asm volatile("s_barrier" ::: "memory");
  };

  // prologue: tiles 0,1 in flight; wait tile0 landed (tile1's 4 outstanding)
  stage_tile(0);
  stage_tile(1);
  asm volatile("s_waitcnt vmcnt(4)" ::: "memory");
  asm volatile("s_barrier" ::: "memory");

  for (int T = 0; T < 30; ++T) phase(T, 1);
  phase(30, 2);    // tile31 is the only outstanding group -> drain
  phase(31, 0);

  const int col_l = l & 15;
  const int row_l = (l >> 4) * 4;
  const int b_ = bm >> 11;

  if (which != 2) {
    // Q/K: bf16 out [B,H,S,HD], scaled (verbatim R2 STORE=1)
    const float scl = which == 0 ? 0.18033688011112042f : 1.0f;
    unsigned short* out = which == 0 ? Qo : Ko;
#pragma unroll
    for (int ii = 0; ii < 4; ++ii) {
      int m_base = bm + wm + ii * 16 + row_l;
#pragma unroll
      for (int j = 0; j < 4; ++j) {
        int n = bn + wn + j * 16 + col_l;
        float bv = bias[n];
        int h_ = n >> 6, hd_ = n & 63;
#pragma unroll
        for (int r = 0; r < 4; ++r) {
          int m = m_base + r;
          int b2 = m >> 11, s_ = m & 2047;
          out[(((size_t)(b2 * HH + h_) * SS) + s_) * HD + hd_] =
              f2bf((acc[ii][j][r] + bv) * scl);
        }
      }
    }
  } else {
    // V: transpose 128x128 C tile via LDS (verbatim R2 STORE=2), store
    // VTo[(b*HH+h)*HD+hd][s] with 256 B contiguous runs along s.
    unsigned short* out = VTo;
    unsigned int* Tt = (unsigned int*)&lds[0][0][0];  // 2048 dwords scratch
    const int srow0 = bm & 2047;
#pragma unroll
    for (int p = 0; p < 4; ++p) {
      __syncthreads();
      if ((w & 1) == (p >> 1)) {
        const int jt0 = (p & 1) * 2;
#pragma unroll
        for (int jj = 0; jj < 2; ++jj) {
          int jt = jt0 + jj;
          int n_p = jj * 16 + col_l;          // n within pass [0,32)
          float bv = bias[bn + p * 32 + n_p];
#pragma unroll
          for (int ii = 0; ii < 4; ++ii) {
            int m0 = wm + ii * 16 + row_l;    // even
#pragma unroll
            for (int pr = 0; pr < 2; ++pr) {
              unsigned int val =
                  (unsigned int)f2bf(acc[ii][jt][2 * pr] + bv) |
                  ((unsigned int)f2bf(acc[ii][jt][2 * pr + 1] + bv) << 16);
              int m = m0 + 2 * pr;
              Tt[n_p * 64 + (((m >> 1)) ^ ((n_p & 7) << 2))] = val;
            }
          }
        }
      }
      __syncthreads();
#pragma unroll
      for (int cq = 0; cq < 2; ++cq) {
        int q = t + cq * 256;
        int n_p = q >> 4, cpos = q & 15;
        uint4 v = *(const uint4*)(Tt + n_p * 64 + ((cpos * 4) ^ ((n_p & 7) << 2)));
        int n_glob = bn + p * 32 + n_p;
        int h_ = n_glob >> 6, hd_ = n_glob & 63;
        *(uint4*)(out + ((size_t)((b_ * HH + h_) * HD + hd_)) * SS + srow0 + cpos * 8) = v;
      }
    }
  }
}

// ---------------------------------------------------------------------------
// MFMA flash attention v12 (unchanged from R8, passed): 16 q-rows/wave,
// 32-key parity subtiles, 33 KB LDS, 4 blocks/CU, bh-fastest grid,
// hoisted addressing, permlane P redistribution.
// ---------------------------------------------------------------------------
__global__ __launch_bounds__(512, 4) void flash_attn_mfma(
    const unsigned short* __restrict__ Q,   // [B,H,S,HD] bf16 (pre-scaled)
    const unsigned short* __restrict__ K,   // [B,H,S,HD] bf16
    const unsigned short* __restrict__ VT,  // [B,H,HD,S] bf16
    unsigned short* __restrict__ ctx) {     // [B,S,D] bf16
  const int bh = blockIdx.x;   // FASTEST: XCD = bh % 8 -> per-XCD K/V locality
  const int qt = blockIdx.y;   // 64-row q tile
  const int b  = bh >> 4;
  const int h  = bh & 15;
  const int t  = threadIdx.x;
  const int w  = t >> 6;   // wave 0..7
  const int l  = t & 63;
  const int wg = w & 3;    // q sub-tile 0..3 (16 rows each)
  const int wh = w >> 2;   // key-subtile parity 0/1
  const int g  = l >> 4;   // lane group 0..3
  const int ln = l & 15;   // q index within 16-row tile

  const unsigned short* Qp = Q + ((size_t)bh * SS + (size_t)qt * 64 + wg * 16) * HD;
  const unsigned short* Kp = K + (size_t)bh * SS * HD;
  const unsigned short* Vp = VT + (size_t)bh * HD * SS;

  // [K=0/V=1][parity][dbuf][4 KB tile]; K tile [32key][64hd], V tile [64hd][32key]
  __shared__ __align__(16) unsigned short smem[2][2][2][2048];
  __shared__ __align__(16) float rred[4 * 64];  // 1 KB combine scratch (rs)

  // Q as B-operand fragments: qf[kb], n=ln, k = kb*32 + g*8 + j
  bf16x8 qf[2];
#pragma unroll
  for (int kb = 0; kb < 2; ++kb)
    qf[kb] = *(const bf16x8*)(Qp + ln * HD + kb * 32 + g * 8);

  f32x4 o[4];
#pragma unroll
  for (int mt = 0; mt < 4; ++mt) o[mt] = (f32x4)0.f;
  float rs = 0.f;

  // ---- loop-invariant staging pointers (advance by const stride per tile)
  const int sp  = w >> 2;          // parity this wave stages
  const int sq  = w & 3;           // quarter within parity tile
  const int idx = sq * 64 + l;
  const int rowK = idx >> 3;
  const int gccK = (idx & 7) ^ (rowK & 7);
  const unsigned short* kgp = Kp + (size_t)(sp * 32 + rowK) * HD + gccK * 8;
  const int rowV = idx >> 2;
  const int gc2V = (idx & 3) ^ ((rowV >> 1) & 3);
  const unsigned short* vgp = Vp + (size_t)rowV * SS + sp * 32 + gc2V * 8;
  unsigned short* dK = &smem[0][sp][0][sq * 512];   // +2048 shorts for db=1
  unsigned short* dV = &smem[1][sp][0][sq * 512];

  // ---- loop-invariant ds_read byte offsets (pure lane constants)
  int ko[2][2];
#pragma unroll
  for (int kb = 0; kb < 2; ++kb)
#pragma unroll
    for (int mt = 0; mt < 2; ++mt) {
      int row = mt * 16 + ln;
      ko[kb][mt] = row * 128 + (((kb * 4 + g) ^ (row & 7)) * 16);
    }
  int vo[4];
#pragma unroll
  for (int mt = 0; mt < 4; ++mt) {
    int row = mt * 16 + ln;
    vo[mt] = row * 64 + ((g ^ ((row >> 1) & 3)) * 16);
  }
  const char* kpar = (const char*)&smem[0][wh][0][0];
  const char* vpar = (const char*)&smem[1][wh][0][0];

  auto stage_i = [&](int db) {
    async_copy16(kgp, dK + db * 2048);
    async_copy16(vgp, dV + db * 2048);
    kgp += 64 * HD;   // next 64-key group along s
    vgp += 64;
  };

  auto body = [&](int db) {
    const char* Kst = kpar + db * 4096;
    const char* Vst = vpar + db * 4096;

    // --- S^T = K Q^T : st[mt][r] = S[key = mt*16+4g+r][q = ln]
    f32x4 st[2];
#pragma unroll
    for (int mt = 0; mt < 2; ++mt) st[mt] = (f32x4)0.f;
#pragma unroll
    for (int kb = 0; kb < 2; ++kb)
#pragma unroll
      for (int mt = 0; mt < 2; ++mt) {
        bf16x8 ka = *(const bf16x8*)(Kst + ko[kb][mt]);
        st[mt] = __builtin_amdgcn_mfma_f32_16x16x32_bf16(ka, qf[kb], st[mt], 0, 0, 0);
      }

    // --- p = exp2(s'); pack bf16 pairs in-register; permlane redistribute
    unsigned Sd[2][2];  // [mt][p]: keys mt*16+4g+2p..+1, q=ln
#pragma unroll
    for (int mt = 0; mt < 2; ++mt) {
      float p0 = fast_exp2(st[mt][0]);
      float p1 = fast_exp2(st[mt][1]);
      float p2 = fast_exp2(st[mt][2]);
      float p3 = fast_exp2(st[mt][3]);
      Sd[mt][0] = __builtin_amdgcn_perm(__float_as_uint(p1), __float_as_uint(p0),
                                        0x07060302u);  // lo=p0,hi=p1
      Sd[mt][1] = __builtin_amdgcn_perm(__float_as_uint(p3), __float_as_uint(p2),
                                        0x07060302u);
      rs += (p0 + p1) + (p2 + p3);
    }
    // reg(mt) <-> lane-bit5, then reg <-> lane-bit4
#pragma unroll
    for (int p = 0; p < 2; ++p) pl32_swap(Sd[0][p], Sd[1][p]);
#pragma unroll
    for (int p = 0; p < 2; ++p) pl16_swap(Sd[0][p], Sd[1][p]);
    // Now Sd[i1][i0] = B-frag dword 2*i1+i0: keys g*8+2i..+1.

    // --- O^T += V^T P^T : P B-frag straight from registers (K-dim = 32)
    bf16x8 pbv;
    {
      union { unsigned u[4]; bf16x8 v; } cu;
      cu.u[0] = Sd[0][0];
      cu.u[1] = Sd[0][1];
      cu.u[2] = Sd[1][0];
      cu.u[3] = Sd[1][1];
      pbv = cu.v;
    }
#pragma unroll
    for (int mt = 0; mt < 4; ++mt) {
      bf16x8 va = *(const bf16x8*)(Vst + vo[mt]);
      o[mt] = __builtin_amdgcn_mfma_f32_16x16x32_bf16(va, pbv, o[mt], 0, 0, 0);
    }
  };

  // prologue: tile 0 -> db0
  stage_i(0);
  for (int kt2 = 0; kt2 < 16; ++kt2) {   // 2 key-tiles per iteration
    __syncthreads();                     // db0 ready; db1 free
    stage_i(1);                          // tile 2*kt2+1 -> db1
    body(0);                             // compute tile 2*kt2
    __syncthreads();                     // db1 ready; db0 free
    if (kt2 < 15) stage_i(0);            // tile 2*kt2+2 -> db0
    body(1);                             // compute tile 2*kt2+1
  }

  // --- cross-parity combine: wh=1 waves dump partial o/rs to LDS, wh=0 adds.
  __syncthreads();  // all compute done; smem reusable as scratch
  {
    float* ored = (float*)&smem[0][0][0][0];  // 4 regions x 64 lanes x 16 f32 = 16 KB
    float* rb = ored + (wg * 64 + l) * 16;
    float* sb = rred + wg * 64 + l;
    if (wh == 1) {
#pragma unroll
      for (int mt = 0; mt < 4; ++mt)
        *(f32x4*)(rb + ((unsigned)(mt ^ (l & 3)) * 4)) = o[mt];
      sb[0] = rs;
    }
    __syncthreads();
    if (wh == 1) return;
#pragma unroll
    for (int mt = 0; mt < 4; ++mt) {
      f32x4 pv = *(const f32x4*)(rb + ((unsigned)(mt ^ (l & 3)) * 4));
      o[mt] += pv;
    }
    rs += sb[0];
  }

  // --- epilogue: reduce rs over lane groups, normalize, store bf16 ctx
  {
    float lsum = rs;
    lsum += __shfl_xor(lsum, 16, 64);
    lsum += __shfl_xor(lsum, 32, 64);
    float inv = 1.f / lsum;
    int srow = qt * 64 + wg * 16 + ln;
    unsigned short* cb = ctx + (size_t)(b * SS + srow) * DD + h * HD;
#pragma unroll
    for (int mt = 0; mt < 4; ++mt) {
      ushort4 u4;
      u4.x = f2bf(o[mt][0] * inv);
      u4.y = f2bf(o[mt][1] * inv);
      u4.z = f2bf(o[mt][2] * inv);
      u4.w = f2bf(o[mt][3] * inv);
      *(ushort4*)(cb + mt * 16 + 4 * g) = u4;
    }
  }
}

// ---------------------------------------------------------------------------
extern "C" void kernel_launch(void* const* d_in, const int* in_sizes, int n_in,
                              void* d_out, int out_size, void* d_ws, size_t ws_size,
                              hipStream_t stream) {
  const float* x  = (const float*)d_in[0];
  const float* Wq = (const float*)d_in[1];
  const float* bq = (const float*)d_in[2];
  const float* Wk = (const float*)d_in[3];
  const float* bk = (const float*)d_in[4];
  const float* Wv = (const float*)d_in[5];
  const float* bv = (const float*)d_in[6];
  const float* Wo = (const float*)d_in[7];
  const float* bo = (const float*)d_in[8];
  float* out = (float*)d_out;

  const size_t ELEMS = (size_t)BB * SS * DD;  // 4,194,304
  char* ws = (char*)d_ws;
  unsigned short* xb   = (unsigned short*)ws;  ws += ELEMS * 2;
  unsigned short* WqT  = (unsigned short*)ws;  ws += (size_t)DD * DD * 2;
  unsigned short* WkT  = (unsigned short*)ws;  ws += (size_t)DD * DD * 2;
  unsigned short* WvT  = (unsigned short*)ws;  ws += (size_t)DD * DD * 2;
  unsigned short* WoT  = (unsigned short*)ws;  ws += (size_t)DD * DD * 2;
  unsigned short* Qb   = (unsigned short*)ws;  ws += ELEMS * 2;
  unsigned short* Kb   = (unsigned short*)ws;  ws += ELEMS * 2;
  unsigned short* VbT  = (unsigned short*)ws;  ws += ELEMS * 2;
  unsigned short* ctxb = (unsigned short*)ws;  ws += ELEMS * 2;

  prep_kernel<<<8192, 256, 0, stream>>>(x, xb, Wq, WqT, Wk, WkT, Wv, WvT, Wo, WoT);

  qkv_gemm_tri<<<768, 256, 0, stream>>>(xb, WqT, WkT, WvT, bq, bk, bv,
                                        Qb, Kb, VbT);

  dim3 attn_grid(BB * HH, SS / 64);            // (32 bh, 32 qt) = 1024 blocks
  flash_attn_mfma<<<attn_grid, 512, 0, stream>>>(Qb, Kb, VbT, ctxb);

  out_gemm_mfma<<<256, 256, 0, stream>>>(ctxb, WoT, bo, out);
}

// Round 10
// 185.374 us; speedup vs baseline: 1.6771x; 1.0451x over previous
//
#include <hip/hip_runtime.h>
#include <hip/hip_bf16.h>

#define BB 2
#define SS 2048
#define DD 1024
#define HH 16
#define HD 64

typedef __attribute__((ext_vector_type(8))) short bf16x8;
typedef __attribute__((ext_vector_type(4))) float f32x4;

// round-to-nearest-even f32 -> bf16 (inputs finite)
__device__ __forceinline__ unsigned short f2bf(float f) {
  unsigned int u = __float_as_uint(f);
  return (unsigned short)((u + 0x7FFFu + ((u >> 16) & 1u)) >> 16);
}

// 2^x via hardware v_exp_f32
__device__ __forceinline__ float fast_exp2(float x) {
#if __has_builtin(__builtin_amdgcn_exp2f)
  return __builtin_amdgcn_exp2f(x);
#else
  return __expf(x * 0.6931471805599453f);
#endif
}

__device__ __forceinline__ void async_copy16(const unsigned short* gp, unsigned short* lp) {
  __builtin_amdgcn_global_load_lds(
      (const __attribute__((address_space(1))) unsigned int*)gp,
      (__attribute__((address_space(3))) unsigned int*)lp, 16, 0, 0);
}

// gfx950 cross-lane register swaps (VALU, not DS pipe).
__device__ __forceinline__ void pl32_swap(unsigned& a, unsigned& b) {
#if __has_builtin(__builtin_amdgcn_permlane32_swap)
  auto r = __builtin_amdgcn_permlane32_swap(a, b, false, false);
  a = r[0];
  b = r[1];
#else
  asm volatile("v_permlane32_swap_b32 %0, %1" : "+v"(a), "+v"(b));
#endif
}
__device__ __forceinline__ void pl16_swap(unsigned& a, unsigned& b) {
#if __has_builtin(__builtin_amdgcn_permlane16_swap)
  auto r = __builtin_amdgcn_permlane16_swap(a, b, false, false);
  a = r[0];
  b = r[1];
#else
  asm volatile("v_permlane16_swap_b32 %0, %1" : "+v"(a), "+v"(b));
#endif
}

// ---------------------------------------------------------------------------
// Fused prep: blocks [0,4096) convert x -> bf16; blocks [4096,8192) transpose
// one of the 4 weight matrices (1024 32x32 tiles each) to bf16 [N][K].
// ---------------------------------------------------------------------------
__global__ __launch_bounds__(256) void prep_kernel(
    const float* __restrict__ x, unsigned short* __restrict__ xb,
    const float* __restrict__ W0, unsigned short* __restrict__ T0,
    const float* __restrict__ W1, unsigned short* __restrict__ T1,
    const float* __restrict__ W2, unsigned short* __restrict__ T2,
    const float* __restrict__ W3, unsigned short* __restrict__ T3) {
  const int blk = blockIdx.x;
  const int t = threadIdx.x;
  if (blk < 4096) {
    int i = blk * 1024 + t * 4;
    float4 v = *(const float4*)(x + i);
    ushort4 u;
    u.x = f2bf(v.x); u.y = f2bf(v.y); u.z = f2bf(v.z); u.w = f2bf(v.w);
    *(ushort4*)(xb + i) = u;
    return;
  }
  const int j = blk - 4096;
  const int jw = j >> 10;          // which weight
  const int tb = j & 1023;
  const float* W = jw == 0 ? W0 : (jw == 1 ? W1 : (jw == 2 ? W2 : W3));
  unsigned short* T = jw == 0 ? T0 : (jw == 1 ? T1 : (jw == 2 ? T2 : T3));
  __shared__ float tile[32][33];
  int k0 = (tb & 31) * 32, n0 = (tb >> 5) * 32;
  int c = t & 31, r0 = t >> 5;
#pragma unroll
  for (int i = 0; i < 4; ++i) {
    int r = r0 + i * 8;
    tile[r][c] = W[(size_t)(k0 + r) * DD + n0 + c];
  }
  __syncthreads();
#pragma unroll
  for (int i = 0; i < 4; ++i) {
    int r = r0 + i * 8;
    T[(size_t)(n0 + r) * DD + k0 + c] = f2bf(tile[c][r]);
  }
}

// ---------------------------------------------------------------------------
// bf16 MFMA GEMM core (m97 single-buffer, BK=32): D = A[M,K]@B^T[N,K] + bias
// STORE=0: fp32 out [M][DD]   (used by out-projection only)
// ---------------------------------------------------------------------------
template <int STORE>
__device__ __forceinline__ void gemm_core(
    const unsigned short* __restrict__ A, const unsigned short* __restrict__ BT,
    const float* __restrict__ bias, void* __restrict__ outp, float scale,
    int bm, int bn) {
  const int t = threadIdx.x;
  const int w = t >> 6;
  const int l = t & 63;
  const int wm = (w >> 1) * 64;
  const int wn = (w & 1) * 64;

  __shared__ __align__(16) unsigned short As[128 * 32];
  __shared__ __align__(16) unsigned short Bs[128 * 32];

  f32x4 acc[4][4];
#pragma unroll
  for (int i = 0; i < 4; ++i)
#pragma unroll
    for (int j = 0; j < 4; ++j) acc[i][j] = (f32x4)0.f;

  const int fr = l & 15;
  const int kg = (l >> 4) * 8;

  for (int k0 = 0; k0 < DD; k0 += 32) {
    __syncthreads();
#pragma unroll
    for (int c = 0; c < 2; ++c) {
      int e = (w * 2 + c) * 512 + l * 8;
      int row = e >> 5, kk = e & 31;
      async_copy16(A + (size_t)(bm + row) * DD + k0 + kk, As + (w * 2 + c) * 512);
      async_copy16(BT + (size_t)(bn + row) * DD + k0 + kk, Bs + (w * 2 + c) * 512);
    }
    __syncthreads();

    bf16x8 af[4], bfr[4];
#pragma unroll
    for (int i = 0; i < 4; ++i)
      af[i] = *(const bf16x8*)(As + (wm + i * 16 + fr) * 32 + kg);
#pragma unroll
    for (int j = 0; j < 4; ++j)
      bfr[j] = *(const bf16x8*)(Bs + (wn + j * 16 + fr) * 32 + kg);
#pragma unroll
    for (int i = 0; i < 4; ++i)
#pragma unroll
      for (int j = 0; j < 4; ++j)
        acc[i][j] = __builtin_amdgcn_mfma_f32_16x16x32_bf16(af[i], bfr[j], acc[i][j], 0, 0, 0);
  }

  const int col_l = l & 15;
  const int row_l = (l >> 4) * 4;

#pragma unroll
  for (int i = 0; i < 4; ++i) {
    int m_base = bm + wm + i * 16 + row_l;
#pragma unroll
    for (int j = 0; j < 4; ++j) {
      int n = bn + wn + j * 16 + col_l;
      float bv = bias[n];
      float* out = (float*)outp;
#pragma unroll
      for (int r = 0; r < 4; ++r)
        out[(size_t)(m_base + r) * DD + n] = acc[i][j][r] + bv;
    }
  }
}

// output projection, 256 blocks, XCD-swizzled (8 bn per bm on one XCD)
__global__ __launch_bounds__(256) void out_gemm_mfma(
    const unsigned short* __restrict__ A, const unsigned short* __restrict__ WoT,
    const float* __restrict__ bo, float* __restrict__ out) {
  const int i = blockIdx.x;
  const int xcd = i & 7;
  const int slot = i >> 3;            // 0..31
  const int bm = (xcd + 8 * (slot >> 3)) * 128;
  const int bn = (slot & 7) * 128;
  gemm_core<0>(A, WoT, bo, (void*)out, 1.0f, bm, bn);
}

// ---------------------------------------------------------------------------
// QKV projection v2 (verified R9: left top-5): 128x128xBK32, 768 blocks,
// triple-buffered LDS, counted-vmcnt raw-asm schedule, setprio.
// ---------------------------------------------------------------------------
__global__ __launch_bounds__(256, 3) void qkv_gemm_tri(
    const unsigned short* __restrict__ A,
    const unsigned short* __restrict__ WqT, const unsigned short* __restrict__ WkT,
    const unsigned short* __restrict__ WvT,
    const float* __restrict__ bq, const float* __restrict__ bk,
    const float* __restrict__ bv,
    unsigned short* __restrict__ Qo, unsigned short* __restrict__ Ko,
    unsigned short* __restrict__ VTo) {
  const int i = blockIdx.x;
  const int xcd = i & 7;
  const int slot = i >> 3;              // 0..95
  const int bm = (xcd + 8 * (slot / 24)) * 128;   // 24 blocks share A-panel/XCD
  const int c = slot % 24;
  const int which = c >> 3;             // 0:Q 1:K 2:V
  const int bn = (c & 7) * 128;
  const unsigned short* BT = which == 0 ? WqT : (which == 1 ? WkT : WvT);
  const float* bias = which == 0 ? bq : (which == 1 ? bk : bv);

  const int t = threadIdx.x;
  const int w = t >> 6;
  const int l = t & 63;
  const int wm = (w >> 1) * 64;
  const int wn = (w & 1) * 64;
  const int fr = l & 15;
  const int kgB = (l >> 4) * 16;        // byte offset of lane's k-group

  // [A=0/B=1][tri][128 rows x 32 k] bf16 = 48 KB -> 3 blocks/CU
  __shared__ __align__(16) unsigned short lds[2][3][4096];

  f32x4 acc[4][4];
#pragma unroll
  for (int ii = 0; ii < 4; ++ii)
#pragma unroll
    for (int j = 0; j < 4; ++j) acc[ii][j] = (f32x4)0.f;

  // hoisted LDS read byte offsets (lane constants)
  int aoff[4], boff[4];
#pragma unroll
  for (int ii = 0; ii < 4; ++ii) {
    aoff[ii] = (wm + ii * 16 + fr) * 64 + kgB;
    boff[ii] = (wn + ii * 16 + fr) * 64 + kgB;
  }

  // hoisted staging source pointers (advance by literal k0 per tile)
  const int cc0 = w * 128 + l;          // (w*2+0)*64 + l
  const int cc1 = cc0 + 64;
  const int row0 = cc0 >> 2, kk0 = (cc0 & 3) * 8;
  const int row1 = cc1 >> 2, kk1 = (cc1 & 3) * 8;
  const unsigned short* a0 = A + (size_t)(bm + row0) * DD + kk0;
  const unsigned short* a1 = A + (size_t)(bm + row1) * DD + kk1;
  const unsigned short* b0 = BT + (size_t)(bn + row0) * DD + kk0;
  const unsigned short* b1 = BT + (size_t)(bn + row1) * DD + kk1;

  auto stage_tile = [&](int T) {
    if (T >= 32) return;
    const int buf = T % 3;
    const int k0 = T * 32;
    async_copy16(a0 + k0, &lds[0][buf][w * 1024]);
    async_copy16(a1 + k0, &lds[0][buf][w * 1024 + 512]);
    async_copy16(b0 + k0, &lds[1][buf][w * 1024]);
    async_copy16(b1 + k0, &lds[1][buf][w * 1024 + 512]);
  };

  auto phase = [&](int T, int vm) {
    const int buf = T % 3;
    const char* Ab = (const char*)&lds[0][buf][0];
    const char* Bb = (const char*)&lds[1][buf][0];
    bf16x8 af[4], bfr[4];
#pragma unroll
    for (int ii = 0; ii < 4; ++ii) af[ii] = *(const bf16x8*)(Ab + aoff[ii]);
#pragma unroll
    for (int j = 0; j < 4; ++j) bfr[j] = *(const bf16x8*)(Bb + boff[j]);
    stage_tile(T + 2);
    asm volatile("s_barrier" ::: "memory");
    __builtin_amdgcn_s_setprio(1);
#pragma unroll
    for (int ii = 0; ii < 4; ++ii)
#pragma unroll
      for (int j = 0; j < 4; ++j)
        acc[ii][j] = __builtin_amdgcn_mfma_f32_16x16x32_bf16(af[ii], bfr[j], acc[ii][j], 0, 0, 0);
    __builtin_amdgcn_s_setprio(0);
    if (vm == 1) asm volatile("s_waitcnt vmcnt(4)" ::: "memory");
    if (vm == 2) asm volatile("s_waitcnt vmcnt(0)" ::: "memory");
    asm volatile("s_barrier" ::: "memory");
  };

  // prologue: tiles 0,1 in flight; wait tile0 landed (tile1's 4 outstanding)
  stage_tile(0);
  stage_tile(1);
  asm volatile("s_waitcnt vmcnt(4)" ::: "memory");
  asm volatile("s_barrier" ::: "memory");

  for (int T = 0; T < 30; ++T) phase(T, 1);
  phase(30, 2);    // tile31 is the only outstanding group -> drain
  phase(31, 0);

  const int col_l = l & 15;
  const int row_l = (l >> 4) * 4;
  const int b_ = bm >> 11;

  if (which != 2) {
    // Q/K: bf16 out [B,H,S,HD], scaled
    const float scl = which == 0 ? 0.18033688011112042f : 1.0f;
    unsigned short* out = which == 0 ? Qo : Ko;
#pragma unroll
    for (int ii = 0; ii < 4; ++ii) {
      int m_base = bm + wm + ii * 16 + row_l;
#pragma unroll
      for (int j = 0; j < 4; ++j) {
        int n = bn + wn + j * 16 + col_l;
        float bv = bias[n];
        int h_ = n >> 6, hd_ = n & 63;
#pragma unroll
        for (int r = 0; r < 4; ++r) {
          int m = m_base + r;
          int b2 = m >> 11, s_ = m & 2047;
          out[(((size_t)(b2 * HH + h_) * SS) + s_) * HD + hd_] =
              f2bf((acc[ii][j][r] + bv) * scl);
        }
      }
    }
  } else {
    // V: transpose 128x128 C tile via LDS, store VTo[(b*HH+h)*HD+hd][s]
    unsigned short* out = VTo;
    unsigned int* Tt = (unsigned int*)&lds[0][0][0];  // 2048 dwords scratch
    const int srow0 = bm & 2047;
#pragma unroll
    for (int p = 0; p < 4; ++p) {
      __syncthreads();
      if ((w & 1) == (p >> 1)) {
        const int jt0 = (p & 1) * 2;
#pragma unroll
        for (int jj = 0; jj < 2; ++jj) {
          int jt = jt0 + jj;
          int n_p = jj * 16 + col_l;          // n within pass [0,32)
          float bv = bias[bn + p * 32 + n_p];
#pragma unroll
          for (int ii = 0; ii < 4; ++ii) {
            int m0 = wm + ii * 16 + row_l;    // even
#pragma unroll
            for (int pr = 0; pr < 2; ++pr) {
              unsigned int val =
                  (unsigned int)f2bf(acc[ii][jt][2 * pr] + bv) |
                  ((unsigned int)f2bf(acc[ii][jt][2 * pr + 1] + bv) << 16);
              int m = m0 + 2 * pr;
              Tt[n_p * 64 + (((m >> 1)) ^ ((n_p & 7) << 2))] = val;
            }
          }
        }
      }
      __syncthreads();
#pragma unroll
      for (int cq = 0; cq < 2; ++cq) {
        int q = t + cq * 256;
        int n_p = q >> 4, cpos = q & 15;
        uint4 v = *(const uint4*)(Tt + n_p * 64 + ((cpos * 4) ^ ((n_p & 7) << 2)));
        int n_glob = bn + p * 32 + n_p;
        int h_ = n_glob >> 6, hd_ = n_glob & 63;
        *(uint4*)(out + ((size_t)((b_ * HH + h_) * HD + hd_)) * SS + srow0 + cpos * 8) = v;
      }
    }
  }
}

// ---------------------------------------------------------------------------
// MFMA flash attention v13: LDS-traffic fix. R9 audit: v12 is LDS-read-bound
// (32 waves x 32 iters x 8 ds_read_b128 x ~10cyc ~ 41us of DS-pipe time/CU;
// VALU 22us, MFMA 4us). Cause: 16 q/wave halves the work amortized per K/V
// fragment read vs v8 (1/64 vs 1/128 reads per q*k). v13 restores 32 q/wave
// (nt=2): each K/V fragment read feeds 2 MFMA -> LDS traffic halves. Block =
// 128 q x 2 parities (8 waves), 32-key subtiles, 34 KB LDS, grid (32 bh,
// 16 qt) = 512 blocks (2/CU, 16 waves/CU). __launch_bounds__(512,2) ->
// 128-VGPR cap (state ~90; the v9 spill was the (512,8)->32-reg cap).
// Keeps v12's hoisted addressing + v11's bh-fastest grid. Geometry/algebra
// correctness-verified in R5 (v9 passed, absmax 4.9e-4).
// ---------------------------------------------------------------------------
__global__ __launch_bounds__(512, 2) void flash_attn_mfma(
    const unsigned short* __restrict__ Q,   // [B,H,S,HD] bf16 (pre-scaled)
    const unsigned short* __restrict__ K,   // [B,H,S,HD] bf16
    const unsigned short* __restrict__ VT,  // [B,H,HD,S] bf16
    unsigned short* __restrict__ ctx) {     // [B,S,D] bf16
  const int bh = blockIdx.x;   // FASTEST: XCD = bh % 8 -> per-XCD K/V locality
  const int qt = blockIdx.y;   // 128-row q tile
  const int b  = bh >> 4;
  const int h  = bh & 15;
  const int t  = threadIdx.x;
  const int w  = t >> 6;   // wave 0..7
  const int l  = t & 63;
  const int wg = w & 3;    // q sub-tile 0..3 (32 rows each)
  const int wh = w >> 2;   // key-subtile parity 0/1
  const int g  = l >> 4;   // lane group 0..3
  const int ln = l & 15;   // q index within 16-row tile

  const unsigned short* Qp = Q + ((size_t)bh * SS + (size_t)qt * 128 + wg * 32) * HD;
  const unsigned short* Kp = K + (size_t)bh * SS * HD;
  const unsigned short* Vp = VT + (size_t)bh * HD * SS;

  // [K=0/V=1][parity][dbuf][4 KB tile]; K tile [32key][64hd], V tile [64hd][32key]
  __shared__ __align__(16) unsigned short smem[2][2][2][2048];
  __shared__ __align__(16) float rred[4 * 64 * 2];  // 2 KB combine scratch (rs)

  // Q as B-operand fragments: qf[nt][kb], n=ln, k = kb*32 + g*8 + j
  bf16x8 qf[2][2];
#pragma unroll
  for (int nt = 0; nt < 2; ++nt)
#pragma unroll
    for (int kb = 0; kb < 2; ++kb)
      qf[nt][kb] = *(const bf16x8*)(Qp + (nt * 16 + ln) * HD + kb * 32 + g * 8);

  f32x4 o[2][4];
#pragma unroll
  for (int nt = 0; nt < 2; ++nt)
#pragma unroll
    for (int mt = 0; mt < 4; ++mt) o[nt][mt] = (f32x4)0.f;
  float rs[2] = {0.f, 0.f};

  // ---- loop-invariant staging pointers (advance by const stride per tile)
  const int sp  = w >> 2;          // parity this wave stages
  const int sq  = w & 3;           // quarter within parity tile
  const int idx = sq * 64 + l;
  const int rowK = idx >> 3;
  const int gccK = (idx & 7) ^ (rowK & 7);
  const unsigned short* kgp = Kp + (size_t)(sp * 32 + rowK) * HD + gccK * 8;
  const int rowV = idx >> 2;
  const int gc2V = (idx & 3) ^ ((rowV >> 1) & 3);
  const unsigned short* vgp = Vp + (size_t)rowV * SS + sp * 32 + gc2V * 8;
  unsigned short* dK = &smem[0][sp][0][sq * 512];   // +2048 shorts for db=1
  unsigned short* dV = &smem[1][sp][0][sq * 512];

  // ---- loop-invariant ds_read byte offsets (pure lane constants)
  int ko[2][2];
#pragma unroll
  for (int kb = 0; kb < 2; ++kb)
#pragma unroll
    for (int mt = 0; mt < 2; ++mt) {
      int row = mt * 16 + ln;
      ko[kb][mt] = row * 128 + (((kb * 4 + g) ^ (row & 7)) * 16);
    }
  int vo[4];
#pragma unroll
  for (int mt = 0; mt < 4; ++mt) {
    int row = mt * 16 + ln;
    vo[mt] = row * 64 + ((g ^ ((row >> 1) & 3)) * 16);
  }
  const char* kpar = (const char*)&smem[0][wh][0][0];
  const char* vpar = (const char*)&smem[1][wh][0][0];

  auto stage_i = [&](int db) {
    async_copy16(kgp, dK + db * 2048);
    async_copy16(vgp, dV + db * 2048);
    kgp += 64 * HD;   // next 64-key group along s
    vgp += 64;
  };

  auto body = [&](int db) {
    const char* Kst = kpar + db * 4096;
    const char* Vst = vpar + db * 4096;

    // --- S^T = K Q^T : st[nt][mt][r] = S[key = mt*16+4g+r][q = nt*16+ln]
    f32x4 st[2][2];
#pragma unroll
    for (int nt = 0; nt < 2; ++nt)
#pragma unroll
      for (int mt = 0; mt < 2; ++mt) st[nt][mt] = (f32x4)0.f;
#pragma unroll
    for (int kb = 0; kb < 2; ++kb)
#pragma unroll
      for (int mt = 0; mt < 2; ++mt) {
        bf16x8 ka = *(const bf16x8*)(Kst + ko[kb][mt]);   // 1 read -> 2 MFMA
        st[0][mt] = __builtin_amdgcn_mfma_f32_16x16x32_bf16(ka, qf[0][kb], st[0][mt], 0, 0, 0);
        st[1][mt] = __builtin_amdgcn_mfma_f32_16x16x32_bf16(ka, qf[1][kb], st[1][mt], 0, 0, 0);
      }

    // --- p = exp2(s'); pack bf16 pairs in-register; permlane redistribute
    unsigned Sd[2][2][2];  // [nt][mt][p]: keys mt*16+4g+2p..+1, q=nt*16+ln
#pragma unroll
    for (int nt = 0; nt < 2; ++nt) {
#pragma unroll
      for (int mt = 0; mt < 2; ++mt) {
        float p0 = fast_exp2(st[nt][mt][0]);
        float p1 = fast_exp2(st[nt][mt][1]);
        float p2 = fast_exp2(st[nt][mt][2]);
        float p3 = fast_exp2(st[nt][mt][3]);
        Sd[nt][mt][0] = __builtin_amdgcn_perm(__float_as_uint(p1), __float_as_uint(p0),
                                              0x07060302u);  // lo=p0,hi=p1
        Sd[nt][mt][1] = __builtin_amdgcn_perm(__float_as_uint(p3), __float_as_uint(p2),
                                              0x07060302u);
        rs[nt] += (p0 + p1) + (p2 + p3);
      }
      // reg(mt) <-> lane-bit5, then reg <-> lane-bit4
#pragma unroll
      for (int p = 0; p < 2; ++p) pl32_swap(Sd[nt][0][p], Sd[nt][1][p]);
#pragma unroll
      for (int p = 0; p < 2; ++p) pl16_swap(Sd[nt][0][p], Sd[nt][1][p]);
    }
    // Now Sd[nt][i1][i0] = B-frag dword 2*i1+i0: keys g*8+2i..+1.

    // --- O^T += V^T P^T : P B-frags straight from registers (K-dim = 32)
    bf16x8 pbv[2];
#pragma unroll
    for (int nt = 0; nt < 2; ++nt) {
      union { unsigned u[4]; bf16x8 v; } cu;
      cu.u[0] = Sd[nt][0][0];
      cu.u[1] = Sd[nt][0][1];
      cu.u[2] = Sd[nt][1][0];
      cu.u[3] = Sd[nt][1][1];
      pbv[nt] = cu.v;
    }
#pragma unroll
    for (int mt = 0; mt < 4; ++mt) {
      bf16x8 va = *(const bf16x8*)(Vst + vo[mt]);         // 1 read -> 2 MFMA
      o[0][mt] = __builtin_amdgcn_mfma_f32_16x16x32_bf16(va, pbv[0], o[0][mt], 0, 0, 0);
      o[1][mt] = __builtin_amdgcn_mfma_f32_16x16x32_bf16(va, pbv[1], o[1][mt], 0, 0, 0);
    }
  };

  // prologue: key-group 0 -> db0
  stage_i(0);
  for (int kt2 = 0; kt2 < 16; ++kt2) {   // 2 key-groups per iteration
    __syncthreads();                     // db0 ready; db1 free
    stage_i(1);                          // group 2*kt2+1 -> db1
    body(0);                             // compute group 2*kt2
    __syncthreads();                     // db1 ready; db0 free
    if (kt2 < 15) stage_i(0);            // group 2*kt2+2 -> db0
    body(1);                             // compute group 2*kt2+1
  }

  // --- cross-parity combine: wh=1 waves dump partial o/rs to LDS, wh=0 adds.
  __syncthreads();  // all compute done; smem reusable as scratch
  {
    float* ored = (float*)&smem[0][0][0][0];  // 4 regions x 64 lanes x 32 f32 = 32 KB
    float* rb = ored + (wg * 64 + l) * 32;
    float* sb = rred + (wg * 64 + l) * 2;
    if (wh == 1) {
#pragma unroll
      for (int nt = 0; nt < 2; ++nt)
#pragma unroll
        for (int mt = 0; mt < 4; ++mt) {
          int idx2 = nt * 4 + mt;
          *(f32x4*)(rb + ((unsigned)(idx2 ^ (l & 7)) * 4)) = o[nt][mt];
        }
      sb[0] = rs[0];
      sb[1] = rs[1];
    }
    __syncthreads();
    if (wh == 1) return;
#pragma unroll
    for (int nt = 0; nt < 2; ++nt)
#pragma unroll
      for (int mt = 0; mt < 4; ++mt) {
        int idx2 = nt * 4 + mt;
        f32x4 pv = *(const f32x4*)(rb + ((unsigned)(idx2 ^ (l & 7)) * 4));
        o[nt][mt] += pv;
      }
    rs[0] += sb[0];
    rs[1] += sb[1];
  }

  // --- epilogue: reduce rs over lane groups, normalize, store bf16 ctx
#pragma unroll
  for (int nt = 0; nt < 2; ++nt) {
    float lsum = rs[nt];
    lsum += __shfl_xor(lsum, 16, 64);
    lsum += __shfl_xor(lsum, 32, 64);
    float inv = 1.f / lsum;
    int srow = qt * 128 + wg * 32 + nt * 16 + ln;
    unsigned short* cb = ctx + (size_t)(b * SS + srow) * DD + h * HD;
#pragma unroll
    for (int mt = 0; mt < 4; ++mt) {
      ushort4 u4;
      u4.x = f2bf(o[nt][mt][0] * inv);
      u4.y = f2bf(o[nt][mt][1] * inv);
      u4.z = f2bf(o[nt][mt][2] * inv);
      u4.w = f2bf(o[nt][mt][3] * inv);
      *(ushort4*)(cb + mt * 16 + 4 * g) = u4;
    }
  }
}

// ---------------------------------------------------------------------------
extern "C" void kernel_launch(void* const* d_in, const int* in_sizes, int n_in,
                              void* d_out, int out_size, void* d_ws, size_t ws_size,
                              hipStream_t stream) {
  const float* x  = (const float*)d_in[0];
  const float* Wq = (const float*)d_in[1];
  const float* bq = (const float*)d_in[2];
  const float* Wk = (const float*)d_in[3];
  const float* bk = (const float*)d_in[4];
  const float* Wv = (const float*)d_in[5];
  const float* bv = (const float*)d_in[6];
  const float* Wo = (const float*)d_in[7];
  const float* bo = (const float*)d_in[8];
  float* out = (float*)d_out;

  const size_t ELEMS = (size_t)BB * SS * DD;  // 4,194,304
  char* ws = (char*)d_ws;
  unsigned short* xb   = (unsigned short*)ws;  ws += ELEMS * 2;
  unsigned short* WqT  = (unsigned short*)ws;  ws += (size_t)DD * DD * 2;
  unsigned short* WkT  = (unsigned short*)ws;  ws += (size_t)DD * DD * 2;
  unsigned short* WvT  = (unsigned short*)ws;  ws += (size_t)DD * DD * 2;
  unsigned short* WoT  = (unsigned short*)ws;  ws += (size_t)DD * DD * 2;
  unsigned short* Qb   = (unsigned short*)ws;  ws += ELEMS * 2;
  unsigned short* Kb   = (unsigned short*)ws;  ws += ELEMS * 2;
  unsigned short* VbT  = (unsigned short*)ws;  ws += ELEMS * 2;
  unsigned short* ctxb = (unsigned short*)ws;  ws += ELEMS * 2;

  prep_kernel<<<8192, 256, 0, stream>>>(x, xb, Wq, WqT, Wk, WkT, Wv, WvT, Wo, WoT);

  qkv_gemm_tri<<<768, 256, 0, stream>>>(xb, WqT, WkT, WvT, bq, bk, bv,
                                        Qb, Kb, VbT);

  dim3 attn_grid(BB * HH, SS / 128);           // (32 bh, 16 qt) = 512 blocks
  flash_attn_mfma<<<attn_grid, 512, 0, stream>>>(Qb, Kb, VbT, ctxb);

  out_gemm_mfma<<<256, 256, 0, stream>>>(ctxb, WoT, bo, out);
}